// Round 11
// baseline (281.878 us; speedup 1.0000x reference)
//
#include <hip/hip_runtime.h>
#include <math.h>

#define BB   2
#define CC   256
#define NPT  4096
#define HH   4
#define DD   64
#define KNN  16
#define EPSBN 1e-5f

typedef __attribute__((ext_vector_type(8))) short short8;
typedef __attribute__((ext_vector_type(4))) float f32x4;

__device__ __forceinline__ unsigned short f2b(float f) {
  union { float f; unsigned int u; } v; v.f = f;
  unsigned int r = (v.u + 0x7FFFu + ((v.u >> 16) & 1u)) >> 16;
  return (unsigned short)r;
}
__device__ __forceinline__ float b2f(unsigned short h) {
  union { unsigned int u; float f; } v; v.u = ((unsigned int)h) << 16;
  return v.f;
}
__device__ __forceinline__ void up2(unsigned int u, float& a, float& b) {
  union { unsigned int x; float f; } lo, hi;
  lo.x = u << 16; hi.x = u & 0xffff0000u;
  a = lo.f; b = hi.f;
}
__device__ __forceinline__ void up16(uint4 u0, uint4 u1, float* f) {
  up2(u0.x, f[0], f[1]);  up2(u0.y, f[2], f[3]);
  up2(u0.z, f[4], f[5]);  up2(u0.w, f[6], f[7]);
  up2(u1.x, f[8], f[9]);  up2(u1.y, f[10], f[11]);
  up2(u1.z, f[12], f[13]); up2(u1.w, f[14], f[15]);
}

// ---------------- wcast + prep fused: blocks 0..3071 cast weights; block 3072 preps --
__global__ __launch_bounds__(256)
void wcast_kernel(const float* __restrict__ Wq, const float* __restrict__ Wkv,
                  const float* __restrict__ Wp, const float* __restrict__ W1,
                  const float* __restrict__ W2,
                  unsigned short* __restrict__ oQKV, unsigned short* __restrict__ oP,
                  unsigned short* __restrict__ o1,   unsigned short* __restrict__ o2,
                  const float* __restrict__ rp_w1, const float* __restrict__ rp_g,
                  const float* __restrict__ rp_b,  const float* __restrict__ rp_m,
                  const float* __restrict__ rp_v,  const float* __restrict__ rp_w2,
                  float4* __restrict__ w1f, float4* __restrict__ W2t) {
  if (blockIdx.x == 3072) {            // prep: fold rp BN into w1, reduce rp_w2 over heads
    int c = threadIdx.x;
    float s  = rp_g[c] / sqrtf(rp_v[c] + EPSBN);
    float b0 = rp_b[c] - rp_m[c] * s;
    w1f[c] = make_float4(rp_w1[c*3+0]*s, rp_w1[c*3+1]*s, rp_w1[c*3+2]*s, b0);
    float a0=0.f,a1=0.f,a2=0.f,a3=0.f;
    for (int o = 0; o < 64; o++) {
      a0 += rp_w2[(      o)*CC + c];
      a1 += rp_w2[( 64 + o)*CC + c];
      a2 += rp_w2[(128 + o)*CC + c];
      a3 += rp_w2[(192 + o)*CC + c];
    }
    W2t[c] = make_float4(a0,a1,a2,a3);
    return;
  }
  int i = blockIdx.x * 256 + threadIdx.x;          // 786432 total
  if (i < 65536)        oQKV[i] = f2b(Wq[i]);
  else if (i < 196608)  oQKV[i] = f2b(Wkv[i - 65536]);
  else if (i < 262144)  oP[i - 196608] = f2b(Wp[i - 196608]);
  else if (i < 524288)  o1[i - 262144] = f2b(W1[i - 262144]);
  else                  o2[i - 524288] = f2b(W2[i - 524288]);
}

// ---------------- transpose+cast x: [B][C][N] fp32 -> [B][N][C] bf16 + fp32 --------
__global__ __launch_bounds__(256)
void xcast_kernel(const float* __restrict__ x, unsigned short* __restrict__ xb,
                  float* __restrict__ xf) {
  __shared__ float T[64][65];
  int n0 = blockIdx.x * 64, c0 = blockIdx.y * 64, bb = blockIdx.z;
  int tid = threadIdx.x;
  {
    int crow = tid >> 2, ns = (tid & 3) * 16;
    const float* xp = x + ((size_t)(bb*CC + c0 + crow))*NPT + n0 + ns;
#pragma unroll
    for (int i = 0; i < 4; i++) {
      float4 v = ((const float4*)xp)[i];
      T[crow][ns + i*4 + 0] = v.x; T[crow][ns + i*4 + 1] = v.y;
      T[crow][ns + i*4 + 2] = v.z; T[crow][ns + i*4 + 3] = v.w;
    }
  }
  __syncthreads();
  {
    int nrow = tid >> 2, cs = (tid & 3) * 16;
    float vals[16];
#pragma unroll
    for (int i = 0; i < 16; i++) vals[i] = T[cs + i][nrow];
    size_t orow = ((size_t)(bb*NPT + n0 + nrow))*CC + c0 + cs;
#pragma unroll
    for (int i = 0; i < 4; i++)
      *(float4*)&xf[orow + i*4] = make_float4(vals[i*4], vals[i*4+1], vals[i*4+2], vals[i*4+3]);
    unsigned short us[16];
#pragma unroll
    for (int i = 0; i < 16; i++) us[i] = f2b(vals[i]);
    *(uint4*)&xb[orow]     = *(const uint4*)&us[0];
    *(uint4*)&xb[orow + 8] = *(const uint4*)&us[8];
  }
}

// ---------------- KNN stage 1: packed-u32 min/max network, TWO independent lists ----
// key = (dist_bits & 0xFFFFFE00) | m. Step = v_min_u32 + v_max_u32 (2 VALU).
// R10 post-mortem: one shared list serializes all candidates through a 16-deep
// dependent chain -> VALUBusy capped at 68%. Two lists (even cands -> A, odd -> B)
// give 2 independent chains the scheduler interleaves. Final: insert B's 16 keys
// through A's network (repeated-insertion invariant => A = exact top-16 of all 128;
// packed keys unique => identical result to the single-list version).
#define MSTEPA(K) { unsigned int t = min(key, K); key = max(key, K); K = t; }
#define MPROCA(M4, MI) { \
    float nd = fmaf(qx2, (M4).x, fmaf(qy2, (M4).y, fmaf(qz2, (M4).z, (M4).w + qsq))); \
    nd = fmaxf(nd, 0.f); \
    unsigned int key = (__float_as_uint(nd) & 0xFFFFFE00u) | (unsigned int)(MI); \
    MSTEPA(k0)  MSTEPA(k1)  MSTEPA(k2)  MSTEPA(k3) \
    MSTEPA(k4)  MSTEPA(k5)  MSTEPA(k6)  MSTEPA(k7) \
    MSTEPA(k8)  MSTEPA(k9)  MSTEPA(k10) MSTEPA(k11) \
    MSTEPA(k12) MSTEPA(k13) MSTEPA(k14) MSTEPA(k15) }
#define MPROCB(M4, MI) { \
    float nd = fmaf(qx2, (M4).x, fmaf(qy2, (M4).y, fmaf(qz2, (M4).z, (M4).w + qsq))); \
    nd = fmaxf(nd, 0.f); \
    unsigned int key = (__float_as_uint(nd) & 0xFFFFFE00u) | (unsigned int)(MI); \
    MSTEPA(j0)  MSTEPA(j1)  MSTEPA(j2)  MSTEPA(j3) \
    MSTEPA(j4)  MSTEPA(j5)  MSTEPA(j6)  MSTEPA(j7) \
    MSTEPA(j8)  MSTEPA(j9)  MSTEPA(j10) MSTEPA(j11) \
    MSTEPA(j12) MSTEPA(j13) MSTEPA(j14) MSTEPA(j15) }
#define MINSA(J) { unsigned int key = J; \
    MSTEPA(k0)  MSTEPA(k1)  MSTEPA(k2)  MSTEPA(k3) \
    MSTEPA(k4)  MSTEPA(k5)  MSTEPA(k6)  MSTEPA(k7) \
    MSTEPA(k8)  MSTEPA(k9)  MSTEPA(k10) MSTEPA(k11) \
    MSTEPA(k12) MSTEPA(k13) MSTEPA(k14) MSTEPA(k15) }
__global__ __launch_bounds__(256) __attribute__((amdgpu_waves_per_eu(1, 4)))
void knn_partial_kernel(const float* __restrict__ xyz, float4* __restrict__ Pp) {
  __shared__ float4 sp[512];    // (x, y, z, |p|^2)
  int s  = blockIdx.x;          // candidate slice 0..7
  int qg = blockIdx.y;          // query group 0..63
  int b  = blockIdx.z;
  const float* base = xyz + (size_t)b * 3 * NPT;
  int c0 = s * 512;
  for (int i = threadIdx.x; i < 512; i += 256) {
    float mx = base[c0 + i], my = base[NPT + c0 + i], mz = base[2*NPT + c0 + i];
    sp[i] = make_float4(mx, my, mz, mx*mx + my*my + mz*mz);
  }
  int lane = threadIdx.x & 63;
  int wv   = threadIdx.x >> 6;
  int qn   = qg * 64 + lane;
  float qx = base[qn], qy = base[NPT + qn], qz = base[2*NPT + qn];
  float qsq = qx*qx + qy*qy + qz*qz;
  float qx2 = -2.f*qx, qy2 = -2.f*qy, qz2 = -2.f*qz;
  __syncthreads();

  unsigned int k0=0xFFFFFFFFu,k1=0xFFFFFFFFu,k2=0xFFFFFFFFu,k3=0xFFFFFFFFu,
               k4=0xFFFFFFFFu,k5=0xFFFFFFFFu,k6=0xFFFFFFFFu,k7=0xFFFFFFFFu,
               k8=0xFFFFFFFFu,k9=0xFFFFFFFFu,k10=0xFFFFFFFFu,k11=0xFFFFFFFFu,
               k12=0xFFFFFFFFu,k13=0xFFFFFFFFu,k14=0xFFFFFFFFu,k15=0xFFFFFFFFu;
  unsigned int j0=0xFFFFFFFFu,j1=0xFFFFFFFFu,j2=0xFFFFFFFFu,j3=0xFFFFFFFFu,
               j4=0xFFFFFFFFu,j5=0xFFFFFFFFu,j6=0xFFFFFFFFu,j7=0xFFFFFFFFu,
               j8=0xFFFFFFFFu,j9=0xFFFFFFFFu,j10=0xFFFFFFFFu,j11=0xFFFFFFFFu,
               j12=0xFFFFFFFFu,j13=0xFFFFFFFFu,j14=0xFFFFFFFFu,j15=0xFFFFFFFFu;

  int mbase = wv * 128;
  for (int mm = 0; mm < 128; mm += 4) {
    int m = mbase + mm;
    float4 a = sp[m], bq = sp[m+1], cq = sp[m+2], dq = sp[m+3];  // batched ds_reads
    MPROCA(a,  m)        // even -> list A
    MPROCB(bq, m+1)      // odd  -> list B (independent chain)
    MPROCA(cq, m+2)
    MPROCB(dq, m+3)
  }
  // merge: run B's keys through A's network -> A = exact top-16 of all 128
  MINSA(j0)  MINSA(j1)  MINSA(j2)  MINSA(j3)
  MINSA(j4)  MINSA(j5)  MINSA(j6)  MINSA(j7)
  MINSA(j8)  MINSA(j9)  MINSA(j10) MINSA(j11)
  MINSA(j12) MINSA(j13) MINSA(j14) MINSA(j15)

  int gq = b * NPT + qn;
  float4* out = Pp + (size_t)gq * 256 + (s*4 + wv)*8;   // 128B contiguous per thread
#define UNP(K) __uint_as_float(K & 0xFFFFFE00u), __int_as_float(c0 + (int)(K & 0x1FFu))
  out[0] = make_float4(UNP(k0),  UNP(k1));
  out[1] = make_float4(UNP(k2),  UNP(k3));
  out[2] = make_float4(UNP(k4),  UNP(k5));
  out[3] = make_float4(UNP(k6),  UNP(k7));
  out[4] = make_float4(UNP(k8),  UNP(k9));
  out[5] = make_float4(UNP(k10), UNP(k11));
  out[6] = make_float4(UNP(k12), UNP(k13));
  out[7] = make_float4(UNP(k14), UNP(k15));
#undef UNP
}

// ---------------- KNN stage 2: one WAVE per query, 8 entries/lane, 16 select-min rounds ----
__global__ __launch_bounds__(256)
void knn_merge_kernel(const float4* __restrict__ Pp, int* __restrict__ idx_out) {
  int wv   = threadIdx.x >> 6;
  int lane = threadIdx.x & 63;
  int gq   = blockIdx.x * 4 + wv;
  float d[8]; int ii[8];
  const float4* base = Pp + (size_t)gq * 256;
#pragma unroll
  for (int j = 0; j < 4; j++) {
    float4 v = base[j*64 + lane];
    d[2*j+0] = v.x; ii[2*j+0] = __float_as_int(v.y);
    d[2*j+1] = v.z; ii[2*j+1] = __float_as_int(v.w);
  }
  for (int sel = 0; sel < 16; sel++) {
    float bd = 3.5e38f; int bi = 0x7fffffff;
#pragma unroll
    for (int t = 0; t < 8; t++) {
      bool better = (d[t] < bd) || (d[t] == bd && ii[t] < bi);
      if (better) { bd = d[t]; bi = ii[t]; }
    }
#pragma unroll
    for (int off = 1; off < 64; off <<= 1) {
      float od = __shfl_xor(bd, off, 64);
      int   oi = __shfl_xor(bi, off, 64);
      if (od < bd || (od == bd && oi < bi)) { bd = od; bi = oi; }
    }
#pragma unroll
    for (int t = 0; t < 8; t++)
      if (ii[t] == bi) d[t] = 3.5e38f;
    if (lane == 0) idx_out[gq*16 + sel] = bi;
  }
}

// ---------------- fused attention v3: rel-pos bias computed in-block ----------------
__global__ __launch_bounds__(256, 4)
void attn_kernel(const unsigned short* __restrict__ qkv, const float4* __restrict__ w1f,
                 const float4* __restrict__ W2t, const float* __restrict__ xyz,
                 const int* __restrict__ idx, unsigned short* __restrict__ attn_b) {
  __shared__ float4 sw1[256];
  __shared__ float4 sw2[256];
  __shared__ int   sidx[16];
  __shared__ float srel[16][4];
  __shared__ float sbias[16][4];
  __shared__ float red[4][16*68];
  int tid = threadIdx.x;
  int bn = blockIdx.x;
  int b  = bn >> 12;
  int n  = bn & 4095;
  sw1[tid] = w1f[tid];
  sw2[tid] = W2t[tid];
  if (tid < 16) {
    int j = idx[bn*16 + tid];
    sidx[tid] = j;
    const float* pb = xyz + (size_t)b * 3 * NPT;
    srel[tid][0] = pb[j]         - pb[n];
    srel[tid][1] = pb[NPT + j]   - pb[NPT + n];
    srel[tid][2] = pb[2*NPT + j] - pb[2*NPT + n];
  }
  __syncthreads();
  {  // ---- bias phase ----
    int kk = tid >> 4, cs = tid & 15;
    float rx = srel[kk][0], ry = srel[kk][1], rz = srel[kk][2];
    float h0=0.f,h1=0.f,h2=0.f,h3=0.f;
#pragma unroll
    for (int i = 0; i < 16; i++) {
      int c = cs*16 + ((i + cs) & 15);
      float4 w  = sw1[c];
      float t0 = fmaxf(fmaf(rx, w.x, fmaf(ry, w.y, fmaf(rz, w.z, w.w))), 0.f);
      float4 w2 = sw2[c];
      h0 = fmaf(t0, w2.x, h0); h1 = fmaf(t0, w2.y, h1);
      h2 = fmaf(t0, w2.z, h2); h3 = fmaf(t0, w2.w, h3);
    }
#pragma unroll
    for (int off = 1; off < 16; off <<= 1) {
      h0 += __shfl_xor(h0, off, 64); h1 += __shfl_xor(h1, off, 64);
      h2 += __shfl_xor(h2, off, 64); h3 += __shfl_xor(h3, off, 64);
    }
    if (cs == 0) { sbias[kk][0]=h0; sbias[kk][1]=h1; sbias[kk][2]=h2; sbias[kk][3]=h3; }
  }
  __syncthreads();
  // ---- attention phase ----
  int wv   = tid >> 6;              // head
  int lane = tid & 63;
  int k    = lane >> 2;             // neighbor
  int c4   = lane & 3;              // channel chunk
  int ch0  = wv*64 + c4*16;
  size_t rowq = (size_t)bn * 768;
  size_t base = (size_t)(b*NPT) * 768;

  float qf[16];
  {
    uint4 q0 = *(const uint4*)(qkv + rowq + ch0);
    uint4 q1 = *(const uint4*)(qkv + rowq + ch0 + 8);
    up16(q0, q1, qf);
  }
  int j = sidx[k];
  float dot = 0.f;
  {
    const unsigned short* krow = qkv + base + (size_t)j*768 + 256 + ch0;
    uint4 k0 = *(const uint4*)(krow);
    uint4 k1 = *(const uint4*)(krow + 8);
    float kf[16];
    up16(k0, k1, kf);
#pragma unroll
    for (int i = 0; i < 16; i++) dot = fmaf(qf[i], kf[i], dot);
  }
  dot += __shfl_xor(dot, 1, 64);
  dot += __shfl_xor(dot, 2, 64);
  float logit = dot * 0.125f + sbias[k][wv];
  float mx = logit;
#pragma unroll
  for (int off = 4; off < 64; off <<= 1) mx = fmaxf(mx, __shfl_xor(mx, off, 64));
  float e = __expf(logit - mx);
  float ssum = e;
#pragma unroll
  for (int off = 4; off < 64; off <<= 1) ssum += __shfl_xor(ssum, off, 64);
  float w = e / ssum;

  {
    const unsigned short* vrow = qkv + base + (size_t)j*768 + 512 + ch0;
    uint4 v0 = *(const uint4*)(vrow);
    uint4 v1 = *(const uint4*)(vrow + 8);
    float vf[16];
    up16(v0, v1, vf);
    float* dst = &red[wv][k*68 + c4*16];
#pragma unroll
    for (int g = 0; g < 4; g++)
      ((float4*)dst)[g] = make_float4(w*vf[g*4], w*vf[g*4+1], w*vf[g*4+2], w*vf[g*4+3]);
  }
  __syncthreads();
  float o = 0.f;
#pragma unroll
  for (int kk = 0; kk < 16; kk++) o += red[wv][kk*68 + lane];   // 2-way = free
  attn_b[(size_t)bn*256 + wv*64 + lane] = f2b(o);
}

// ---------------- MFMA bf16 GEMM: D[n][m] = A[n][k] * W[m][k] ----------------
struct MG {
  const unsigned short* A; const unsigned short* Wt; int K; int M;
  unsigned short* OutB; float* OutF;
  const float* bias; const float* resid;
  const float* bng; const float* bnb; const float* bnm; const float* bnv;
};

template<int EPI>
__global__ __launch_bounds__(256)
void mgemm_kernel(MG p) {
  __shared__ unsigned short As[128][40];
  __shared__ unsigned short Bs[64][40];
  const int tid  = threadIdx.x;
  const int bb   = blockIdx.z;
  const int n0   = blockIdx.x * 128;
  const int m0   = blockIdx.y * 64;
  const int lane = tid & 63;
  const int wv   = tid >> 6;
  const int l15  = lane & 15;
  const int quad = lane >> 4;
  const int K    = p.K;

  f32x4 acc[2][4];
#pragma unroll
  for (int i = 0; i < 2; i++)
#pragma unroll
    for (int j = 0; j < 4; j++) acc[i][j] = (f32x4){0.f, 0.f, 0.f, 0.f};

  const int arow = tid >> 1, ahalf = tid & 1;
  const int wrow = tid >> 2, wseg = tid & 3;
  const unsigned short* Ap = p.A  + (size_t)(bb*NPT + n0 + arow)*K + ahalf*16;
  const unsigned short* Wp = p.Wt + (size_t)(m0 + wrow)*K + wseg*8;

  for (int c0 = 0; c0 < K; c0 += 32) {
    uint4 va0 = *(const uint4*)(Ap + c0);
    uint4 va1 = *(const uint4*)(Ap + c0 + 8);
    uint4 vw  = *(const uint4*)(Wp + c0);
    *(uint4*)&As[arow][ahalf*16]     = va0;
    *(uint4*)&As[arow][ahalf*16 + 8] = va1;
    *(uint4*)&Bs[wrow][wseg*8]       = vw;
    __syncthreads();
    short8 bf[4];
#pragma unroll
    for (int mt = 0; mt < 4; mt++)
      bf[mt] = *(const short8*)&Bs[mt*16 + l15][quad*8];
#pragma unroll
    for (int nt = 0; nt < 2; nt++) {
      short8 af = *(const short8*)&As[wv*32 + nt*16 + l15][quad*8];
#pragma unroll
      for (int mt = 0; mt < 4; mt++)
        acc[nt][mt] = __builtin_amdgcn_mfma_f32_16x16x32_bf16(af, bf[mt], acc[nt][mt], 0, 0, 0);
    }
    __syncthreads();
  }

  if (EPI == 0 || EPI == 1) {
    float bs[4];
#pragma unroll
    for (int mt = 0; mt < 4; mt++)
      bs[mt] = (EPI == 1) ? p.bias[m0 + mt*16 + l15] : 0.f;
#pragma unroll
    for (int nt = 0; nt < 2; nt++)
#pragma unroll
      for (int reg = 0; reg < 4; reg++) {
        size_t row = ((size_t)(bb*NPT + n0 + wv*32 + nt*16 + quad*4 + reg))*p.M + m0;
#pragma unroll
        for (int mt = 0; mt < 4; mt++) {
          float v = acc[nt][mt][reg] + bs[mt];
          if (EPI == 1) v = fmaxf(v, 0.f);
          p.OutB[row + mt*16 + l15] = f2b(v);
        }
      }
  } else if (EPI == 2) {
    float sc[4], sh[4];
#pragma unroll
    for (int mt = 0; mt < 4; mt++) {
      int m = m0 + mt*16 + l15;
      float s = p.bng[m] / sqrtf(p.bnv[m] + EPSBN);
      sc[mt] = s; sh[mt] = p.bnb[m] - p.bnm[m]*s;
    }
#pragma unroll
    for (int nt = 0; nt < 2; nt++)
#pragma unroll
      for (int reg = 0; reg < 4; reg++) {
        size_t row = ((size_t)(bb*NPT + n0 + wv*32 + nt*16 + quad*4 + reg))*p.M + m0;
#pragma unroll
        for (int mt = 0; mt < 4; mt++) {
          float r = p.resid[row + mt*16 + l15];
          float v = (acc[nt][mt][reg] + r)*sc[mt] + sh[mt];
          p.OutF[row + mt*16 + l15] = v;
          p.OutB[row + mt*16 + l15] = f2b(v);
        }
      }
  } else {  // EPI == 3
    __shared__ float Tb[4][4][16*17];
    float sc[4], sh[4], bs[4];
#pragma unroll
    for (int mt = 0; mt < 4; mt++) {
      int m = m0 + mt*16 + l15;
      float s = p.bng[m] / sqrtf(p.bnv[m] + EPSBN);
      sc[mt] = s; sh[mt] = p.bnb[m] - p.bnm[m]*s;
      bs[mt] = p.bias[m];
    }
#pragma unroll
    for (int nt = 0; nt < 2; nt++) {
#pragma unroll
      for (int reg = 0; reg < 4; reg++) {
        size_t row = ((size_t)(bb*NPT + n0 + wv*32 + nt*16 + quad*4 + reg))*p.M + m0;
#pragma unroll
        for (int mt = 0; mt < 4; mt++) {
          float r = p.resid[row + mt*16 + l15];
          float v = (acc[nt][mt][reg] + bs[mt] + r)*sc[mt] + sh[mt];
          Tb[wv][mt][(quad*4 + reg)*17 + l15] = v;
        }
      }
      __syncthreads();
#pragma unroll
      for (int mt = 0; mt < 4; mt++)
#pragma unroll
        for (int reg = 0; reg < 4; reg++) {
          float v = Tb[wv][mt][l15*17 + quad*4 + reg];
          p.OutF[((size_t)(bb*p.M + m0 + mt*16 + quad*4 + reg))*NPT
                 + n0 + wv*32 + nt*16 + l15] = v;
        }
      __syncthreads();
    }
  }
}

extern "C" void kernel_launch(void* const* d_in, const int* in_sizes, int n_in,
                              void* d_out, int out_size, void* d_ws, size_t ws_size,
                              hipStream_t stream) {
  const float* x     = (const float*)d_in[0];
  const float* xyz   = (const float*)d_in[1];
  const float* Wq    = (const float*)d_in[2];
  const float* Wkv   = (const float*)d_in[3];
  const float* Wproj = (const float*)d_in[4];
  const float* rp_w1 = (const float*)d_in[5];
  const float* rp_g  = (const float*)d_in[6];
  const float* rp_b  = (const float*)d_in[7];
  const float* rp_m  = (const float*)d_in[8];
  const float* rp_v  = (const float*)d_in[9];
  const float* rp_w2 = (const float*)d_in[10];
  const float* bn1_g = (const float*)d_in[11];
  const float* bn1_b = (const float*)d_in[12];
  const float* bn1_m = (const float*)d_in[13];
  const float* bn1_v = (const float*)d_in[14];
  const float* bn2_g = (const float*)d_in[15];
  const float* bn2_b = (const float*)d_in[16];
  const float* bn2_m = (const float*)d_in[17];
  const float* bn2_v = (const float*)d_in[18];
  const float* ffn_w1 = (const float*)d_in[19];
  const float* ffn_b1 = (const float*)d_in[20];
  const float* ffn_w2 = (const float*)d_in[21];
  const float* ffn_b2 = (const float*)d_in[22];

  char* ws = (char*)d_ws;
  // static region
  float4* w1f = (float4*)(ws + 0);                         //   4 KB
  float4* W2t = (float4*)(ws + 4096);                      //   4 KB
  int*    idx = (int*)  (ws + 8192);                       // 512 KB
  // reuse region A (32 MB): KNN scratch first, then post-attn tensors
  const size_t oA = 532480;
  float4*         Pp     = (float4*)(ws + oA);             // 32 MB [B*N][512] (d,idx)
  unsigned short* attn_b = (unsigned short*)(ws + oA);                 //  4 MB bf16 [B][N][256]
  float*          x1f    = (float*)(ws + oA + (4u<<20));               //  8 MB fp32 [B][N][256]
  unsigned short* x1b    = (unsigned short*)(ws + oA + (12u<<20));     //  4 MB bf16 [B][N][256]
  unsigned short* h_b    = (unsigned short*)(ws + oA + (16u<<20));     // 16 MB bf16 [B][N][1024]
  // region B: weights + casted x + qkv
  const size_t oB = oA + (32u<<20);
  unsigned short* Wqkv_b  = (unsigned short*)(ws + oB);                // 384 KB [768][256]
  unsigned short* Wproj_b = (unsigned short*)(ws + oB + 393216);       // 128 KB
  unsigned short* W1_b    = (unsigned short*)(ws + oB + 524288);       // 512 KB
  unsigned short* W2_b    = (unsigned short*)(ws + oB + 1048576);      // 512 KB
  unsigned short* xb      = (unsigned short*)(ws + oB + 1572864);      //   4 MB bf16 [B][N][256]
  float*          xf      = (float*)(ws + oB + 1572864 + (4u<<20));    //   8 MB fp32 [B][N][256]
  unsigned short* qkv     = (unsigned short*)(ws + oB + 1572864 + (12u<<20)); // 12 MB bf16 [B][N][768]

  wcast_kernel<<<3073, 256, 0, stream>>>(Wq, Wkv, Wproj, ffn_w1, ffn_w2,
                                         Wqkv_b, Wproj_b, W1_b, W2_b,
                                         rp_w1, rp_g, rp_b, rp_m, rp_v, rp_w2, w1f, W2t);
  xcast_kernel<<<dim3(64, 4, BB), 256, 0, stream>>>(x, xb, xf);

  knn_partial_kernel<<<dim3(8, 64, BB), 256, 0, stream>>>(xyz, Pp);
  knn_merge_kernel<<<(BB*NPT)/4, 256, 0, stream>>>(Pp, idx);

  MG pqkv = {xb, Wqkv_b, 256, 768, qkv, nullptr,
             nullptr, nullptr, nullptr, nullptr, nullptr, nullptr};
  mgemm_kernel<0><<<dim3(32, 12, BB), 256, 0, stream>>>(pqkv);

  attn_kernel<<<BB*NPT, 256, 0, stream>>>(qkv, w1f, W2t, xyz, idx, attn_b);

  MG pproj = {attn_b, Wproj_b, 256, 256, x1b, x1f,
              nullptr, xf, bn1_g, bn1_b, bn1_m, bn1_v};
  mgemm_kernel<2><<<dim3(32, 4, BB), 256, 0, stream>>>(pproj);

  MG pf1 = {x1b, W1_b, 256, 1024, h_b, nullptr,
            ffn_b1, nullptr, nullptr, nullptr, nullptr, nullptr};
  mgemm_kernel<1><<<dim3(32, 16, BB), 256, 0, stream>>>(pf1);

  MG pf2 = {h_b, W2_b, 1024, 256, nullptr, (float*)d_out,
            ffn_b2, x1f, bn2_g, bn2_b, bn2_m, bn2_v};
  mgemm_kernel<3><<<dim3(32, 4, BB), 256, 0, stream>>>(pf2);
}

// Round 12
// 267.087 us; speedup vs baseline: 1.0554x; 1.0554x over previous
//
#include <hip/hip_runtime.h>
#include <math.h>

#define BB   2
#define CC   256
#define NPT  4096
#define HH   4
#define DD   64
#define KNN  16
#define EPSBN 1e-5f

typedef __attribute__((ext_vector_type(8))) short short8;
typedef __attribute__((ext_vector_type(4))) float f32x4;

typedef __attribute__((address_space(3))) unsigned int lds_u32;
typedef const __attribute__((address_space(1))) unsigned int glb_u32;
__device__ __forceinline__ void gl_lds16(const void* g, void* l) {
  // async global->LDS DMA, 16B/lane; LDS dst = wave-uniform base + lane*16
  __builtin_amdgcn_global_load_lds((glb_u32*)g, (lds_u32*)l, 16, 0, 0);
}

__device__ __forceinline__ unsigned short f2b(float f) {
  union { float f; unsigned int u; } v; v.f = f;
  unsigned int r = (v.u + 0x7FFFu + ((v.u >> 16) & 1u)) >> 16;
  return (unsigned short)r;
}
__device__ __forceinline__ float b2f(unsigned short h) {
  union { unsigned int u; float f; } v; v.u = ((unsigned int)h) << 16;
  return v.f;
}
__device__ __forceinline__ void up2(unsigned int u, float& a, float& b) {
  union { unsigned int x; float f; } lo, hi;
  lo.x = u << 16; hi.x = u & 0xffff0000u;
  a = lo.f; b = hi.f;
}
__device__ __forceinline__ void up16(uint4 u0, uint4 u1, float* f) {
  up2(u0.x, f[0], f[1]);  up2(u0.y, f[2], f[3]);
  up2(u0.z, f[4], f[5]);  up2(u0.w, f[6], f[7]);
  up2(u1.x, f[8], f[9]);  up2(u1.y, f[10], f[11]);
  up2(u1.z, f[12], f[13]); up2(u1.w, f[14], f[15]);
}

// ---------------- wcast + prep fused: blocks 0..3071 cast weights; block 3072 preps --
__global__ __launch_bounds__(256)
void wcast_kernel(const float* __restrict__ Wq, const float* __restrict__ Wkv,
                  const float* __restrict__ Wp, const float* __restrict__ W1,
                  const float* __restrict__ W2,
                  unsigned short* __restrict__ oQKV, unsigned short* __restrict__ oP,
                  unsigned short* __restrict__ o1,   unsigned short* __restrict__ o2,
                  const float* __restrict__ rp_w1, const float* __restrict__ rp_g,
                  const float* __restrict__ rp_b,  const float* __restrict__ rp_m,
                  const float* __restrict__ rp_v,  const float* __restrict__ rp_w2,
                  float4* __restrict__ w1f, float4* __restrict__ W2t) {
  if (blockIdx.x == 3072) {            // prep: fold rp BN into w1, reduce rp_w2 over heads
    int c = threadIdx.x;
    float s  = rp_g[c] / sqrtf(rp_v[c] + EPSBN);
    float b0 = rp_b[c] - rp_m[c] * s;
    w1f[c] = make_float4(rp_w1[c*3+0]*s, rp_w1[c*3+1]*s, rp_w1[c*3+2]*s, b0);
    float a0=0.f,a1=0.f,a2=0.f,a3=0.f;
    for (int o = 0; o < 64; o++) {
      a0 += rp_w2[(      o)*CC + c];
      a1 += rp_w2[( 64 + o)*CC + c];
      a2 += rp_w2[(128 + o)*CC + c];
      a3 += rp_w2[(192 + o)*CC + c];
    }
    W2t[c] = make_float4(a0,a1,a2,a3);
    return;
  }
  int i = blockIdx.x * 256 + threadIdx.x;          // 786432 total
  if (i < 65536)        oQKV[i] = f2b(Wq[i]);
  else if (i < 196608)  oQKV[i] = f2b(Wkv[i - 65536]);
  else if (i < 262144)  oP[i - 196608] = f2b(Wp[i - 196608]);
  else if (i < 524288)  o1[i - 262144] = f2b(W1[i - 262144]);
  else                  o2[i - 524288] = f2b(W2[i - 524288]);
}

// ---------------- transpose+cast x: [B][C][N] fp32 -> [B][N][C] bf16 + fp32 --------
__global__ __launch_bounds__(256)
void xcast_kernel(const float* __restrict__ x, unsigned short* __restrict__ xb,
                  float* __restrict__ xf) {
  __shared__ float T[64][65];
  int n0 = blockIdx.x * 64, c0 = blockIdx.y * 64, bb = blockIdx.z;
  int tid = threadIdx.x;
  {
    int crow = tid >> 2, ns = (tid & 3) * 16;
    const float* xp = x + ((size_t)(bb*CC + c0 + crow))*NPT + n0 + ns;
#pragma unroll
    for (int i = 0; i < 4; i++) {
      float4 v = ((const float4*)xp)[i];
      T[crow][ns + i*4 + 0] = v.x; T[crow][ns + i*4 + 1] = v.y;
      T[crow][ns + i*4 + 2] = v.z; T[crow][ns + i*4 + 3] = v.w;
    }
  }
  __syncthreads();
  {
    int nrow = tid >> 2, cs = (tid & 3) * 16;
    float vals[16];
#pragma unroll
    for (int i = 0; i < 16; i++) vals[i] = T[cs + i][nrow];
    size_t orow = ((size_t)(bb*NPT + n0 + nrow))*CC + c0 + cs;
#pragma unroll
    for (int i = 0; i < 4; i++)
      *(float4*)&xf[orow + i*4] = make_float4(vals[i*4], vals[i*4+1], vals[i*4+2], vals[i*4+3]);
    unsigned short us[16];
#pragma unroll
    for (int i = 0; i < 16; i++) us[i] = f2b(vals[i]);
    *(uint4*)&xb[orow]     = *(const uint4*)&us[0];
    *(uint4*)&xb[orow + 8] = *(const uint4*)&us[8];
  }
}

// ---------------- KNN stage 1 (R9 version — best measured: 44 µs) ----------------
#define MSTEP(K) { unsigned int t = min(key, K); key = max(key, K); K = t; }
#define MPROC(M4, MI) { \
    float nd = fmaf(qx2, (M4).x, fmaf(qy2, (M4).y, fmaf(qz2, (M4).z, (M4).w + qsq))); \
    nd = fmaxf(nd, 0.f); \
    unsigned int key = (__float_as_uint(nd) & 0xFFFFFE00u) | (unsigned int)(MI); \
    MSTEP(k0)  MSTEP(k1)  MSTEP(k2)  MSTEP(k3) \
    MSTEP(k4)  MSTEP(k5)  MSTEP(k6)  MSTEP(k7) \
    MSTEP(k8)  MSTEP(k9)  MSTEP(k10) MSTEP(k11) \
    MSTEP(k12) MSTEP(k13) MSTEP(k14) MSTEP(k15) }
__global__ __launch_bounds__(256) __attribute__((amdgpu_waves_per_eu(1, 4)))
void knn_partial_kernel(const float* __restrict__ xyz, float4* __restrict__ Pp) {
  __shared__ float4 sp[512];    // (x, y, z, |p|^2)
  int s  = blockIdx.x;          // candidate slice 0..7
  int qg = blockIdx.y;          // query group 0..63
  int b  = blockIdx.z;
  const float* base = xyz + (size_t)b * 3 * NPT;
  int c0 = s * 512;
  for (int i = threadIdx.x; i < 512; i += 256) {
    float mx = base[c0 + i], my = base[NPT + c0 + i], mz = base[2*NPT + c0 + i];
    sp[i] = make_float4(mx, my, mz, mx*mx + my*my + mz*mz);
  }
  int lane = threadIdx.x & 63;
  int wv   = threadIdx.x >> 6;
  int qn   = qg * 64 + lane;
  float qx = base[qn], qy = base[NPT + qn], qz = base[2*NPT + qn];
  float qsq = qx*qx + qy*qy + qz*qz;
  float qx2 = -2.f*qx, qy2 = -2.f*qy, qz2 = -2.f*qz;
  __syncthreads();

  unsigned int k0=0xFFFFFFFFu,k1=0xFFFFFFFFu,k2=0xFFFFFFFFu,k3=0xFFFFFFFFu,
               k4=0xFFFFFFFFu,k5=0xFFFFFFFFu,k6=0xFFFFFFFFu,k7=0xFFFFFFFFu,
               k8=0xFFFFFFFFu,k9=0xFFFFFFFFu,k10=0xFFFFFFFFu,k11=0xFFFFFFFFu,
               k12=0xFFFFFFFFu,k13=0xFFFFFFFFu,k14=0xFFFFFFFFu,k15=0xFFFFFFFFu;

  int mbase = wv * 128;
  for (int mm = 0; mm < 128; mm += 4) {
    int m = mbase + mm;
    float4 a = sp[m], bq = sp[m+1], cq = sp[m+2], dq = sp[m+3];  // batched ds_reads
    MPROC(a,  m)
    MPROC(bq, m+1)
    MPROC(cq, m+2)
    MPROC(dq, m+3)
  }

  int gq = b * NPT + qn;
  float4* out = Pp + (size_t)gq * 256 + (s*4 + wv)*8;   // 128B contiguous per thread
#define UNP(K) __uint_as_float(K & 0xFFFFFE00u), __int_as_float(c0 + (int)(K & 0x1FFu))
  out[0] = make_float4(UNP(k0),  UNP(k1));
  out[1] = make_float4(UNP(k2),  UNP(k3));
  out[2] = make_float4(UNP(k4),  UNP(k5));
  out[3] = make_float4(UNP(k6),  UNP(k7));
  out[4] = make_float4(UNP(k8),  UNP(k9));
  out[5] = make_float4(UNP(k10), UNP(k11));
  out[6] = make_float4(UNP(k12), UNP(k13));
  out[7] = make_float4(UNP(k14), UNP(k15));
#undef UNP
}

// ---------------- KNN stage 2: one WAVE per query, 8 entries/lane, 16 select-min rounds ----
__global__ __launch_bounds__(256)
void knn_merge_kernel(const float4* __restrict__ Pp, int* __restrict__ idx_out) {
  int wv   = threadIdx.x >> 6;
  int lane = threadIdx.x & 63;
  int gq   = blockIdx.x * 4 + wv;
  float d[8]; int ii[8];
  const float4* base = Pp + (size_t)gq * 256;
#pragma unroll
  for (int j = 0; j < 4; j++) {
    float4 v = base[j*64 + lane];
    d[2*j+0] = v.x; ii[2*j+0] = __float_as_int(v.y);
    d[2*j+1] = v.z; ii[2*j+1] = __float_as_int(v.w);
  }
  for (int sel = 0; sel < 16; sel++) {
    float bd = 3.5e38f; int bi = 0x7fffffff;
#pragma unroll
    for (int t = 0; t < 8; t++) {
      bool better = (d[t] < bd) || (d[t] == bd && ii[t] < bi);
      if (better) { bd = d[t]; bi = ii[t]; }
    }
#pragma unroll
    for (int off = 1; off < 64; off <<= 1) {
      float od = __shfl_xor(bd, off, 64);
      int   oi = __shfl_xor(bi, off, 64);
      if (od < bd || (od == bd && oi < bi)) { bd = od; bi = oi; }
    }
#pragma unroll
    for (int t = 0; t < 8; t++)
      if (ii[t] == bi) d[t] = 3.5e38f;
    if (lane == 0) idx_out[gq*16 + sel] = bi;
  }
}

// ---------------- fused attention v3: rel-pos bias computed in-block ----------------
__global__ __launch_bounds__(256, 4)
void attn_kernel(const unsigned short* __restrict__ qkv, const float4* __restrict__ w1f,
                 const float4* __restrict__ W2t, const float* __restrict__ xyz,
                 const int* __restrict__ idx, unsigned short* __restrict__ attn_b) {
  __shared__ float4 sw1[256];
  __shared__ float4 sw2[256];
  __shared__ int   sidx[16];
  __shared__ float srel[16][4];
  __shared__ float sbias[16][4];
  __shared__ float red[4][16*68];
  int tid = threadIdx.x;
  int bn = blockIdx.x;
  int b  = bn >> 12;
  int n  = bn & 4095;
  sw1[tid] = w1f[tid];
  sw2[tid] = W2t[tid];
  if (tid < 16) {
    int j = idx[bn*16 + tid];
    sidx[tid] = j;
    const float* pb = xyz + (size_t)b * 3 * NPT;
    srel[tid][0] = pb[j]         - pb[n];
    srel[tid][1] = pb[NPT + j]   - pb[NPT + n];
    srel[tid][2] = pb[2*NPT + j] - pb[2*NPT + n];
  }
  __syncthreads();
  {  // ---- bias phase ----
    int kk = tid >> 4, cs = tid & 15;
    float rx = srel[kk][0], ry = srel[kk][1], rz = srel[kk][2];
    float h0=0.f,h1=0.f,h2=0.f,h3=0.f;
#pragma unroll
    for (int i = 0; i < 16; i++) {
      int c = cs*16 + ((i + cs) & 15);
      float4 w  = sw1[c];
      float t0 = fmaxf(fmaf(rx, w.x, fmaf(ry, w.y, fmaf(rz, w.z, w.w))), 0.f);
      float4 w2 = sw2[c];
      h0 = fmaf(t0, w2.x, h0); h1 = fmaf(t0, w2.y, h1);
      h2 = fmaf(t0, w2.z, h2); h3 = fmaf(t0, w2.w, h3);
    }
#pragma unroll
    for (int off = 1; off < 16; off <<= 1) {
      h0 += __shfl_xor(h0, off, 64); h1 += __shfl_xor(h1, off, 64);
      h2 += __shfl_xor(h2, off, 64); h3 += __shfl_xor(h3, off, 64);
    }
    if (cs == 0) { sbias[kk][0]=h0; sbias[kk][1]=h1; sbias[kk][2]=h2; sbias[kk][3]=h3; }
  }
  __syncthreads();
  // ---- attention phase ----
  int wv   = tid >> 6;              // head
  int lane = tid & 63;
  int k    = lane >> 2;             // neighbor
  int c4   = lane & 3;              // channel chunk
  int ch0  = wv*64 + c4*16;
  size_t rowq = (size_t)bn * 768;
  size_t base = (size_t)(b*NPT) * 768;

  float qf[16];
  {
    uint4 q0 = *(const uint4*)(qkv + rowq + ch0);
    uint4 q1 = *(const uint4*)(qkv + rowq + ch0 + 8);
    up16(q0, q1, qf);
  }
  int j = sidx[k];
  float dot = 0.f;
  {
    const unsigned short* krow = qkv + base + (size_t)j*768 + 256 + ch0;
    uint4 k0 = *(const uint4*)(krow);
    uint4 k1 = *(const uint4*)(krow + 8);
    float kf[16];
    up16(k0, k1, kf);
#pragma unroll
    for (int i = 0; i < 16; i++) dot = fmaf(qf[i], kf[i], dot);
  }
  dot += __shfl_xor(dot, 1, 64);
  dot += __shfl_xor(dot, 2, 64);
  float logit = dot * 0.125f + sbias[k][wv];
  float mx = logit;
#pragma unroll
  for (int off = 4; off < 64; off <<= 1) mx = fmaxf(mx, __shfl_xor(mx, off, 64));
  float e = __expf(logit - mx);
  float ssum = e;
#pragma unroll
  for (int off = 4; off < 64; off <<= 1) ssum += __shfl_xor(ssum, off, 64);
  float w = e / ssum;

  {
    const unsigned short* vrow = qkv + base + (size_t)j*768 + 512 + ch0;
    uint4 v0 = *(const uint4*)(vrow);
    uint4 v1 = *(const uint4*)(vrow + 8);
    float vf[16];
    up16(v0, v1, vf);
    float* dst = &red[wv][k*68 + c4*16];
#pragma unroll
    for (int g = 0; g < 4; g++)
      ((float4*)dst)[g] = make_float4(w*vf[g*4], w*vf[g*4+1], w*vf[g*4+2], w*vf[g*4+3]);
  }
  __syncthreads();
  float o = 0.f;
#pragma unroll
  for (int kk = 0; kk < 16; kk++) o += red[wv][kk*68 + lane];   // 2-way = free
  attn_b[(size_t)bn*256 + wv*64 + lane] = f2b(o);
}

// ---------------- MFMA bf16 GEMM v2: BK=64, async global_load_lds, XOR-swizzled LDS --
// D[n][m] = A[n][k] * W[m][k]. Block 128n x 64m, 4 waves (each 32n x 64m), 16 MFMA
// per barrier window (was 8). Staging: 6 global_load_lds dwordx4 issues per chunk
// (async DMA, no VGPR round-trip — the m93->m97 1.69x lever). LDS rows are unpadded
// (DMA needs lane-contiguous dst); bank conflicts broken by XOR seg swizzle applied
// to the per-lane GLOBAL address: phys_seg = logical_seg ^ (row & 7) -> ds_read_b128
// of a 16-row fragment covers banks 0..31 exactly (2-way repeat = free).
struct MG {
  const unsigned short* A; const unsigned short* Wt; int K; int M;
  unsigned short* OutB; float* OutF;
  const float* bias; const float* resid;
  const float* bng; const float* bnb; const float* bnm; const float* bnv;
};

template<int EPI>
__global__ __launch_bounds__(256)
void mgemm_kernel(MG p) {
  __shared__ unsigned short As[128*64];   // [row][64k], row stride 128B
  __shared__ unsigned short Bs[64*64];
  const int tid  = threadIdx.x;
  const int bb   = blockIdx.z;
  const int n0   = blockIdx.x * 128;
  const int m0   = blockIdx.y * 64;
  const int lane = tid & 63;
  const int wv   = tid >> 6;
  const int l15  = lane & 15;
  const int quad = lane >> 4;
  const int K    = p.K;

  f32x4 acc[2][4];
#pragma unroll
  for (int i = 0; i < 2; i++)
#pragma unroll
    for (int j = 0; j < 4; j++) acc[i][j] = (f32x4){0.f, 0.f, 0.f, 0.f};

  const int srow = wv*8 + (lane >> 3);        // staging row within 32-row group
  const int pseg = lane & 7;                  // physical 16B seg
  const unsigned short* Abase = p.A  + (size_t)bb*NPT*K;

  for (int c0 = 0; c0 < K; c0 += 64) {
#pragma unroll
    for (int t = 0; t < 4; t++) {             // A: 128 rows x 64k = 16KB
      int row = t*32 + srow;
      int ls  = pseg ^ (row & 7);
      gl_lds16(Abase + (size_t)(n0 + row)*K + c0 + ls*8,
               &As[wv*512 + t*2048 + lane*8]);
    }
#pragma unroll
    for (int t = 0; t < 2; t++) {             // B: 64 rows x 64k = 8KB
      int row = t*32 + srow;
      int ls  = pseg ^ (row & 7);
      gl_lds16(p.Wt + (size_t)(m0 + row)*K + c0 + ls*8,
               &Bs[wv*512 + t*2048 + lane*8]);
    }
    __syncthreads();
    short8 bf[4][2];
#pragma unroll
    for (int mt = 0; mt < 4; mt++)
#pragma unroll
      for (int kk = 0; kk < 2; kk++) {
        int row = mt*16 + l15;
        int ps  = (kk*4 + quad) ^ (row & 7);
        bf[mt][kk] = *(const short8*)&Bs[row*64 + ps*8];
      }
#pragma unroll
    for (int nt = 0; nt < 2; nt++)
#pragma unroll
      for (int kk = 0; kk < 2; kk++) {
        int row = wv*32 + nt*16 + l15;
        int ps  = (kk*4 + quad) ^ (row & 7);
        short8 af = *(const short8*)&As[row*64 + ps*8];
#pragma unroll
        for (int mt = 0; mt < 4; mt++)
          acc[nt][mt] = __builtin_amdgcn_mfma_f32_16x16x32_bf16(af, bf[mt][kk], acc[nt][mt], 0, 0, 0);
      }
    __syncthreads();
  }

  if (EPI == 0 || EPI == 1) {
    float bs[4];
#pragma unroll
    for (int mt = 0; mt < 4; mt++)
      bs[mt] = (EPI == 1) ? p.bias[m0 + mt*16 + l15] : 0.f;
#pragma unroll
    for (int nt = 0; nt < 2; nt++)
#pragma unroll
      for (int reg = 0; reg < 4; reg++) {
        size_t row = ((size_t)(bb*NPT + n0 + wv*32 + nt*16 + quad*4 + reg))*p.M + m0;
#pragma unroll
        for (int mt = 0; mt < 4; mt++) {
          float v = acc[nt][mt][reg] + bs[mt];
          if (EPI == 1) v = fmaxf(v, 0.f);
          p.OutB[row + mt*16 + l15] = f2b(v);
        }
      }
  } else if (EPI == 2) {
    float sc[4], sh[4];
#pragma unroll
    for (int mt = 0; mt < 4; mt++) {
      int m = m0 + mt*16 + l15;
      float s = p.bng[m] / sqrtf(p.bnv[m] + EPSBN);
      sc[mt] = s; sh[mt] = p.bnb[m] - p.bnm[m]*s;
    }
#pragma unroll
    for (int nt = 0; nt < 2; nt++)
#pragma unroll
      for (int reg = 0; reg < 4; reg++) {
        size_t row = ((size_t)(bb*NPT + n0 + wv*32 + nt*16 + quad*4 + reg))*p.M + m0;
#pragma unroll
        for (int mt = 0; mt < 4; mt++) {
          float r = p.resid[row + mt*16 + l15];
          float v = (acc[nt][mt][reg] + r)*sc[mt] + sh[mt];
          p.OutF[row + mt*16 + l15] = v;
          p.OutB[row + mt*16 + l15] = f2b(v);
        }
      }
  } else {  // EPI == 3
    __shared__ float Tb[4][4][16*17];
    float sc[4], sh[4], bs[4];
#pragma unroll
    for (int mt = 0; mt < 4; mt++) {
      int m = m0 + mt*16 + l15;
      float s = p.bng[m] / sqrtf(p.bnv[m] + EPSBN);
      sc[mt] = s; sh[mt] = p.bnb[m] - p.bnm[m]*s;
      bs[mt] = p.bias[m];
    }
#pragma unroll
    for (int nt = 0; nt < 2; nt++) {
#pragma unroll
      for (int reg = 0; reg < 4; reg++) {
        size_t row = ((size_t)(bb*NPT + n0 + wv*32 + nt*16 + quad*4 + reg))*p.M + m0;
#pragma unroll
        for (int mt = 0; mt < 4; mt++) {
          float r = p.resid[row + mt*16 + l15];
          float v = (acc[nt][mt][reg] + bs[mt] + r)*sc[mt] + sh[mt];
          Tb[wv][mt][(quad*4 + reg)*17 + l15] = v;
        }
      }
      __syncthreads();
#pragma unroll
      for (int mt = 0; mt < 4; mt++)
#pragma unroll
        for (int reg = 0; reg < 4; reg++) {
          float v = Tb[wv][mt][l15*17 + quad*4 + reg];
          p.OutF[((size_t)(bb*p.M + m0 + mt*16 + quad*4 + reg))*NPT
                 + n0 + wv*32 + nt*16 + l15] = v;
        }
      __syncthreads();
    }
  }
}

extern "C" void kernel_launch(void* const* d_in, const int* in_sizes, int n_in,
                              void* d_out, int out_size, void* d_ws, size_t ws_size,
                              hipStream_t stream) {
  const float* x     = (const float*)d_in[0];
  const float* xyz   = (const float*)d_in[1];
  const float* Wq    = (const float*)d_in[2];
  const float* Wkv   = (const float*)d_in[3];
  const float* Wproj = (const float*)d_in[4];
  const float* rp_w1 = (const float*)d_in[5];
  const float* rp_g  = (const float*)d_in[6];
  const float* rp_b  = (const float*)d_in[7];
  const float* rp_m  = (const float*)d_in[8];
  const float* rp_v  = (const float*)d_in[9];
  const float* rp_w2 = (const float*)d_in[10];
  const float* bn1_g = (const float*)d_in[11];
  const float* bn1_b = (const float*)d_in[12];
  const float* bn1_m = (const float*)d_in[13];
  const float* bn1_v = (const float*)d_in[14];
  const float* bn2_g = (const float*)d_in[15];
  const float* bn2_b = (const float*)d_in[16];
  const float* bn2_m = (const float*)d_in[17];
  const float* bn2_v = (const float*)d_in[18];
  const float* ffn_w1 = (const float*)d_in[19];
  const float* ffn_b1 = (const float*)d_in[20];
  const float* ffn_w2 = (const float*)d_in[21];
  const float* ffn_b2 = (const float*)d_in[22];

  char* ws = (char*)d_ws;
  // static region
  float4* w1f = (float4*)(ws + 0);                         //   4 KB
  float4* W2t = (float4*)(ws + 4096);                      //   4 KB
  int*    idx = (int*)  (ws + 8192);                       // 512 KB
  // reuse region A (32 MB): KNN scratch first, then post-attn tensors
  const size_t oA = 532480;
  float4*         Pp     = (float4*)(ws + oA);             // 32 MB [B*N][512] (d,idx)
  unsigned short* attn_b = (unsigned short*)(ws + oA);                 //  4 MB bf16 [B][N][256]
  float*          x1f    = (float*)(ws + oA + (4u<<20));               //  8 MB fp32 [B][N][256]
  unsigned short* x1b    = (unsigned short*)(ws + oA + (12u<<20));     //  4 MB bf16 [B][N][256]
  unsigned short* h_b    = (unsigned short*)(ws + oA + (16u<<20));     // 16 MB bf16 [B][N][1024]
  // region B: weights + casted x + qkv
  const size_t oB = oA + (32u<<20);
  unsigned short* Wqkv_b  = (unsigned short*)(ws + oB);                // 384 KB [768][256]
  unsigned short* Wproj_b = (unsigned short*)(ws + oB + 393216);       // 128 KB
  unsigned short* W1_b    = (unsigned short*)(ws + oB + 524288);       // 512 KB
  unsigned short* W2_b    = (unsigned short*)(ws + oB + 1048576);      // 512 KB
  unsigned short* xb      = (unsigned short*)(ws + oB + 1572864);      //   4 MB bf16 [B][N][256]
  float*          xf      = (float*)(ws + oB + 1572864 + (4u<<20));    //   8 MB fp32 [B][N][256]
  unsigned short* qkv     = (unsigned short*)(ws + oB + 1572864 + (12u<<20)); // 12 MB bf16 [B][N][768]

  wcast_kernel<<<3073, 256, 0, stream>>>(Wq, Wkv, Wproj, ffn_w1, ffn_w2,
                                         Wqkv_b, Wproj_b, W1_b, W2_b,
                                         rp_w1, rp_g, rp_b, rp_m, rp_v, rp_w2, w1f, W2t);
  xcast_kernel<<<dim3(64, 4, BB), 256, 0, stream>>>(x, xb, xf);

  knn_partial_kernel<<<dim3(8, 64, BB), 256, 0, stream>>>(xyz, Pp);
  knn_merge_kernel<<<(BB*NPT)/4, 256, 0, stream>>>(Pp, idx);

  MG pqkv = {xb, Wqkv_b, 256, 768, qkv, nullptr,
             nullptr, nullptr, nullptr, nullptr, nullptr, nullptr};
  mgemm_kernel<0><<<dim3(32, 12, BB), 256, 0, stream>>>(pqkv);

  attn_kernel<<<BB*NPT, 256, 0, stream>>>(qkv, w1f, W2t, xyz, idx, attn_b);

  MG pproj = {attn_b, Wproj_b, 256, 256, x1b, x1f,
              nullptr, xf, bn1_g, bn1_b, bn1_m, bn1_v};
  mgemm_kernel<2><<<dim3(32, 4, BB), 256, 0, stream>>>(pproj);

  MG pf1 = {x1b, W1_b, 256, 1024, h_b, nullptr,
            ffn_b1, nullptr, nullptr, nullptr, nullptr, nullptr};
  mgemm_kernel<1><<<dim3(32, 16, BB), 256, 0, stream>>>(pf1);

  MG pf2 = {h_b, W2_b, 1024, 256, nullptr, (float*)d_out,
            ffn_b2, x1f, bn2_g, bn2_b, bn2_m, bn2_v};
  mgemm_kernel<3><<<dim3(32, 4, BB), 256, 0, stream>>>(pf2);
}

// Round 13
// 254.724 us; speedup vs baseline: 1.1066x; 1.0485x over previous
//
#include <hip/hip_runtime.h>
#include <math.h>

#define BB   2
#define CC   256
#define NPT  4096
#define HH   4
#define DD   64
#define KNN  16
#define EPSBN 1e-5f

typedef __attribute__((ext_vector_type(8))) short short8;
typedef __attribute__((ext_vector_type(4))) float f32x4;

typedef __attribute__((address_space(3))) unsigned int lds_u32;
typedef const __attribute__((address_space(1))) unsigned int glb_u32;
__device__ __forceinline__ void gl_lds16(const void* g, void* l) {
  __builtin_amdgcn_global_load_lds((glb_u32*)g, (lds_u32*)l, 16, 0, 0);
}

__device__ __forceinline__ unsigned short f2b(float f) {
  union { float f; unsigned int u; } v; v.f = f;
  unsigned int r = (v.u + 0x7FFFu + ((v.u >> 16) & 1u)) >> 16;
  return (unsigned short)r;
}
__device__ __forceinline__ void up2(unsigned int u, float& a, float& b) {
  union { unsigned int x; float f; } lo, hi;
  lo.x = u << 16; hi.x = u & 0xffff0000u;
  a = lo.f; b = hi.f;
}
__device__ __forceinline__ void up16(uint4 u0, uint4 u1, float* f) {
  up2(u0.x, f[0], f[1]);  up2(u0.y, f[2], f[3]);
  up2(u0.z, f[4], f[5]);  up2(u0.w, f[6], f[7]);
  up2(u1.x, f[8], f[9]);  up2(u1.y, f[10], f[11]);
  up2(u1.z, f[12], f[13]); up2(u1.w, f[14], f[15]);
}

// ================= stage 1 bodies (independent work, fused dispatch) =================
__device__ __forceinline__
void wcast_body(const float* Wq, const float* Wkv, const float* Wp,
                const float* W1, const float* W2,
                unsigned short* oQKV, unsigned short* oP,
                unsigned short* o1, unsigned short* o2,
                const float* rp_w1, const float* rp_g, const float* rp_b,
                const float* rp_m, const float* rp_v, const float* rp_w2,
                float4* w1f, float4* W2t, int blk) {
  if (blk == 3072) {            // prep: fold rp BN into w1, reduce rp_w2 over heads
    int c = threadIdx.x;
    float s  = rp_g[c] / sqrtf(rp_v[c] + EPSBN);
    float b0 = rp_b[c] - rp_m[c] * s;
    w1f[c] = make_float4(rp_w1[c*3+0]*s, rp_w1[c*3+1]*s, rp_w1[c*3+2]*s, b0);
    float a0=0.f,a1=0.f,a2=0.f,a3=0.f;
    for (int o = 0; o < 64; o++) {
      a0 += rp_w2[(      o)*CC + c];
      a1 += rp_w2[( 64 + o)*CC + c];
      a2 += rp_w2[(128 + o)*CC + c];
      a3 += rp_w2[(192 + o)*CC + c];
    }
    W2t[c] = make_float4(a0,a1,a2,a3);
    return;
  }
  int i = blk * 256 + threadIdx.x;          // 786432 total
  if (i < 65536)        oQKV[i] = f2b(Wq[i]);
  else if (i < 196608)  oQKV[i] = f2b(Wkv[i - 65536]);
  else if (i < 262144)  oP[i - 196608] = f2b(Wp[i - 196608]);
  else if (i < 524288)  o1[i - 262144] = f2b(W1[i - 262144]);
  else                  o2[i - 524288] = f2b(W2[i - 524288]);
}

__device__ __forceinline__
void xcast_body(const float* x, unsigned short* xb, float* xf,
                int bx, int by, int bz) {
  __shared__ float T[64][65];
  int n0 = bx * 64, c0 = by * 64, bb = bz;
  int tid = threadIdx.x;
  {
    int crow = tid >> 2, ns = (tid & 3) * 16;
    const float* xp = x + ((size_t)(bb*CC + c0 + crow))*NPT + n0 + ns;
#pragma unroll
    for (int i = 0; i < 4; i++) {
      float4 v = ((const float4*)xp)[i];
      T[crow][ns + i*4 + 0] = v.x; T[crow][ns + i*4 + 1] = v.y;
      T[crow][ns + i*4 + 2] = v.z; T[crow][ns + i*4 + 3] = v.w;
    }
  }
  __syncthreads();
  {
    int nrow = tid >> 2, cs = (tid & 3) * 16;
    float vals[16];
#pragma unroll
    for (int i = 0; i < 16; i++) vals[i] = T[cs + i][nrow];
    size_t orow = ((size_t)(bb*NPT + n0 + nrow))*CC + c0 + cs;
#pragma unroll
    for (int i = 0; i < 4; i++)
      *(float4*)&xf[orow + i*4] = make_float4(vals[i*4], vals[i*4+1], vals[i*4+2], vals[i*4+3]);
    unsigned short us[16];
#pragma unroll
    for (int i = 0; i < 16; i++) us[i] = f2b(vals[i]);
    *(uint4*)&xb[orow]     = *(const uint4*)&us[0];
    *(uint4*)&xb[orow + 8] = *(const uint4*)&us[8];
  }
}

// KNN stage 1 (R9 plateau version): packed-u32 min/max sorted-insert network
#define MSTEP(K) { unsigned int t = min(key, K); key = max(key, K); K = t; }
#define MPROC(M4, MI) { \
    float nd = fmaf(qx2, (M4).x, fmaf(qy2, (M4).y, fmaf(qz2, (M4).z, (M4).w + qsq))); \
    nd = fmaxf(nd, 0.f); \
    unsigned int key = (__float_as_uint(nd) & 0xFFFFFE00u) | (unsigned int)(MI); \
    MSTEP(k0)  MSTEP(k1)  MSTEP(k2)  MSTEP(k3) \
    MSTEP(k4)  MSTEP(k5)  MSTEP(k6)  MSTEP(k7) \
    MSTEP(k8)  MSTEP(k9)  MSTEP(k10) MSTEP(k11) \
    MSTEP(k12) MSTEP(k13) MSTEP(k14) MSTEP(k15) }
__device__ __forceinline__
void knn_partial_body(const float* xyz, float4* Pp, int s, int qg, int b) {
  __shared__ float4 sp[512];    // (x, y, z, |p|^2)
  const float* base = xyz + (size_t)b * 3 * NPT;
  int c0 = s * 512;
  for (int i = threadIdx.x; i < 512; i += 256) {
    float mx = base[c0 + i], my = base[NPT + c0 + i], mz = base[2*NPT + c0 + i];
    sp[i] = make_float4(mx, my, mz, mx*mx + my*my + mz*mz);
  }
  int lane = threadIdx.x & 63;
  int wv   = threadIdx.x >> 6;
  int qn   = qg * 64 + lane;
  float qx = base[qn], qy = base[NPT + qn], qz = base[2*NPT + qn];
  float qsq = qx*qx + qy*qy + qz*qz;
  float qx2 = -2.f*qx, qy2 = -2.f*qy, qz2 = -2.f*qz;
  __syncthreads();

  unsigned int k0=0xFFFFFFFFu,k1=0xFFFFFFFFu,k2=0xFFFFFFFFu,k3=0xFFFFFFFFu,
               k4=0xFFFFFFFFu,k5=0xFFFFFFFFu,k6=0xFFFFFFFFu,k7=0xFFFFFFFFu,
               k8=0xFFFFFFFFu,k9=0xFFFFFFFFu,k10=0xFFFFFFFFu,k11=0xFFFFFFFFu,
               k12=0xFFFFFFFFu,k13=0xFFFFFFFFu,k14=0xFFFFFFFFu,k15=0xFFFFFFFFu;

  int mbase = wv * 128;
  for (int mm = 0; mm < 128; mm += 4) {
    int m = mbase + mm;
    float4 a = sp[m], bq = sp[m+1], cq = sp[m+2], dq = sp[m+3];
    MPROC(a,  m)
    MPROC(bq, m+1)
    MPROC(cq, m+2)
    MPROC(dq, m+3)
  }

  int gq = b * NPT + qn;
  float4* out = Pp + (size_t)gq * 256 + (s*4 + wv)*8;
#define UNP(K) __uint_as_float(K & 0xFFFFFE00u), __int_as_float(c0 + (int)(K & 0x1FFu))
  out[0] = make_float4(UNP(k0),  UNP(k1));
  out[1] = make_float4(UNP(k2),  UNP(k3));
  out[2] = make_float4(UNP(k4),  UNP(k5));
  out[3] = make_float4(UNP(k6),  UNP(k7));
  out[4] = make_float4(UNP(k8),  UNP(k9));
  out[5] = make_float4(UNP(k10), UNP(k11));
  out[6] = make_float4(UNP(k12), UNP(k13));
  out[7] = make_float4(UNP(k14), UNP(k15));
#undef UNP
}

// stage1 fused dispatch: [0,512) xcast | [512,3585) wcast | [3585,4609) knn_partial.
// Short memory-bound blocks first so they drain and knn backfills (pipe overlap).
__global__ __launch_bounds__(256) __attribute__((amdgpu_waves_per_eu(1, 4)))
void stage1_kernel(const float* x, unsigned short* xb, float* xf,
                   const float* xyz, float4* Pp,
                   const float* Wq, const float* Wkv, const float* Wp,
                   const float* W1, const float* W2,
                   unsigned short* oQKV, unsigned short* oP,
                   unsigned short* o1, unsigned short* o2,
                   const float* rp_w1, const float* rp_g, const float* rp_b,
                   const float* rp_m, const float* rp_v, const float* rp_w2,
                   float4* w1f, float4* W2t) {
  int bi = blockIdx.x;
  if (bi < 512) {
    xcast_body(x, xb, xf, bi & 63, (bi >> 6) & 3, bi >> 8);
  } else if (bi < 3585) {
    wcast_body(Wq, Wkv, Wp, W1, W2, oQKV, oP, o1, o2,
               rp_w1, rp_g, rp_b, rp_m, rp_v, rp_w2, w1f, W2t, bi - 512);
  } else {
    int i = bi - 3585;
    knn_partial_body(xyz, Pp, i & 7, (i >> 3) & 63, i >> 9);
  }
}

// ================= stage 2: knn_merge + qkv GEMM (independent, fused) ================
__device__ __forceinline__
void knn_merge_body(const float4* Pp, int* idx_out, int blk) {
  int wv   = threadIdx.x >> 6;
  int lane = threadIdx.x & 63;
  int gq   = blk * 4 + wv;
  float d[8]; int ii[8];
  const float4* base = Pp + (size_t)gq * 256;
#pragma unroll
  for (int j = 0; j < 4; j++) {
    float4 v = base[j*64 + lane];
    d[2*j+0] = v.x; ii[2*j+0] = __float_as_int(v.y);
    d[2*j+1] = v.z; ii[2*j+1] = __float_as_int(v.w);
  }
  for (int sel = 0; sel < 16; sel++) {
    float bd = 3.5e38f; int bi = 0x7fffffff;
#pragma unroll
    for (int t = 0; t < 8; t++) {
      bool better = (d[t] < bd) || (d[t] == bd && ii[t] < bi);
      if (better) { bd = d[t]; bi = ii[t]; }
    }
#pragma unroll
    for (int off = 1; off < 64; off <<= 1) {
      float od = __shfl_xor(bd, off, 64);
      int   oi = __shfl_xor(bi, off, 64);
      if (od < bd || (od == bd && oi < bi)) { bd = od; bi = oi; }
    }
#pragma unroll
    for (int t = 0; t < 8; t++)
      if (ii[t] == bi) d[t] = 3.5e38f;
    if (lane == 0) idx_out[gq*16 + sel] = bi;
  }
}

// ---------------- MFMA bf16 GEMM v2 body (R12): BK=64, async DMA, XOR swizzle -------
struct MG {
  const unsigned short* A; const unsigned short* Wt; int K; int M;
  unsigned short* OutB; float* OutF;
  const float* bias; const float* resid;
  const float* bng; const float* bnb; const float* bnm; const float* bnv;
};

template<int EPI>
__device__ __forceinline__ void mgemm_body(const MG& p, int bx, int by, int bz) {
  __shared__ unsigned short As[128*64];
  __shared__ unsigned short Bs[64*64];
  const int tid  = threadIdx.x;
  const int bb   = bz;
  const int n0   = bx * 128;
  const int m0   = by * 64;
  const int lane = tid & 63;
  const int wv   = tid >> 6;
  const int l15  = lane & 15;
  const int quad = lane >> 4;
  const int K    = p.K;

  f32x4 acc[2][4];
#pragma unroll
  for (int i = 0; i < 2; i++)
#pragma unroll
    for (int j = 0; j < 4; j++) acc[i][j] = (f32x4){0.f, 0.f, 0.f, 0.f};

  const int srow = wv*8 + (lane >> 3);
  const int pseg = lane & 7;
  const unsigned short* Abase = p.A  + (size_t)bb*NPT*K;

  for (int c0 = 0; c0 < K; c0 += 64) {
#pragma unroll
    for (int t = 0; t < 4; t++) {
      int row = t*32 + srow;
      int ls  = pseg ^ (row & 7);
      gl_lds16(Abase + (size_t)(n0 + row)*K + c0 + ls*8,
               &As[wv*512 + t*2048 + lane*8]);
    }
#pragma unroll
    for (int t = 0; t < 2; t++) {
      int row = t*32 + srow;
      int ls  = pseg ^ (row & 7);
      gl_lds16(p.Wt + (size_t)(m0 + row)*K + c0 + ls*8,
               &Bs[wv*512 + t*2048 + lane*8]);
    }
    __syncthreads();
    short8 bf[4][2];
#pragma unroll
    for (int mt = 0; mt < 4; mt++)
#pragma unroll
      for (int kk = 0; kk < 2; kk++) {
        int row = mt*16 + l15;
        int ps  = (kk*4 + quad) ^ (row & 7);
        bf[mt][kk] = *(const short8*)&Bs[row*64 + ps*8];
      }
#pragma unroll
    for (int nt = 0; nt < 2; nt++)
#pragma unroll
      for (int kk = 0; kk < 2; kk++) {
        int row = wv*32 + nt*16 + l15;
        int ps  = (kk*4 + quad) ^ (row & 7);
        short8 af = *(const short8*)&As[row*64 + ps*8];
#pragma unroll
        for (int mt = 0; mt < 4; mt++)
          acc[nt][mt] = __builtin_amdgcn_mfma_f32_16x16x32_bf16(af, bf[mt][kk], acc[nt][mt], 0, 0, 0);
      }
    __syncthreads();
  }

  if (EPI == 0 || EPI == 1) {
    float bs[4];
#pragma unroll
    for (int mt = 0; mt < 4; mt++)
      bs[mt] = (EPI == 1) ? p.bias[m0 + mt*16 + l15] : 0.f;
#pragma unroll
    for (int nt = 0; nt < 2; nt++)
#pragma unroll
      for (int reg = 0; reg < 4; reg++) {
        size_t row = ((size_t)(bb*NPT + n0 + wv*32 + nt*16 + quad*4 + reg))*p.M + m0;
#pragma unroll
        for (int mt = 0; mt < 4; mt++) {
          float v = acc[nt][mt][reg] + bs[mt];
          if (EPI == 1) v = fmaxf(v, 0.f);
          p.OutB[row + mt*16 + l15] = f2b(v);
        }
      }
  } else if (EPI == 2) {
    float sc[4], sh[4];
#pragma unroll
    for (int mt = 0; mt < 4; mt++) {
      int m = m0 + mt*16 + l15;
      float s = p.bng[m] / sqrtf(p.bnv[m] + EPSBN);
      sc[mt] = s; sh[mt] = p.bnb[m] - p.bnm[m]*s;
    }
#pragma unroll
    for (int nt = 0; nt < 2; nt++)
#pragma unroll
      for (int reg = 0; reg < 4; reg++) {
        size_t row = ((size_t)(bb*NPT + n0 + wv*32 + nt*16 + quad*4 + reg))*p.M + m0;
#pragma unroll
        for (int mt = 0; mt < 4; mt++) {
          float r = p.resid[row + mt*16 + l15];
          float v = (acc[nt][mt][reg] + r)*sc[mt] + sh[mt];
          p.OutF[row + mt*16 + l15] = v;
          p.OutB[row + mt*16 + l15] = f2b(v);
        }
      }
  } else {  // EPI == 3
    __shared__ float Tb[4][4][16*17];
    float sc[4], sh[4], bs[4];
#pragma unroll
    for (int mt = 0; mt < 4; mt++) {
      int m = m0 + mt*16 + l15;
      float s = p.bng[m] / sqrtf(p.bnv[m] + EPSBN);
      sc[mt] = s; sh[mt] = p.bnb[m] - p.bnm[m]*s;
      bs[mt] = p.bias[m];
    }
#pragma unroll
    for (int nt = 0; nt < 2; nt++) {
#pragma unroll
      for (int reg = 0; reg < 4; reg++) {
        size_t row = ((size_t)(bb*NPT + n0 + wv*32 + nt*16 + quad*4 + reg))*p.M + m0;
#pragma unroll
        for (int mt = 0; mt < 4; mt++) {
          float r = p.resid[row + mt*16 + l15];
          float v = (acc[nt][mt][reg] + bs[mt] + r)*sc[mt] + sh[mt];
          Tb[wv][mt][(quad*4 + reg)*17 + l15] = v;
        }
      }
      __syncthreads();
#pragma unroll
      for (int mt = 0; mt < 4; mt++)
#pragma unroll
        for (int reg = 0; reg < 4; reg++) {
          float v = Tb[wv][mt][l15*17 + quad*4 + reg];
          p.OutF[((size_t)(bb*p.M + m0 + mt*16 + quad*4 + reg))*NPT
                 + n0 + wv*32 + nt*16 + l15] = v;
        }
      __syncthreads();
    }
  }
}

template<int EPI>
__global__ __launch_bounds__(256)
void mgemm_kernel(MG p) { mgemm_body<EPI>(p, blockIdx.x, blockIdx.y, blockIdx.z); }

// stage2 fused: [0,2048) knn_merge | [2048,2816) qkv GEMM (grid 32x12x2 linearized)
__global__ __launch_bounds__(256)
void stage2_kernel(const float4* Pp, int* idx, MG pqkv) {
  int bi = blockIdx.x;
  if (bi < 2048) {
    knn_merge_body(Pp, idx, bi);
  } else {
    int i = bi - 2048;
    mgemm_body<0>(pqkv, i & 31, (i >> 5) % 12, i / 384);
  }
}

// ---------------- fused attention v4: 4 points/block, shared weight reads ----------
// Bias phase: each weight read (sw1[c], sw2[c]) feeds all 4 points' rel vectors ->
// per-point LDS reads cut 4x (R12: bias phase was the LDS-pipe bound, 32 rd_b128/pt).
__global__ __launch_bounds__(256, 4)
void attn_kernel(const unsigned short* __restrict__ qkv, const float4* __restrict__ w1f,
                 const float4* __restrict__ W2t, const float* __restrict__ xyz,
                 const int* __restrict__ idx, unsigned short* __restrict__ attn_b) {
  __shared__ float4 sw1[256];
  __shared__ float4 sw2[256];
  __shared__ int   sidx[4][16];
  __shared__ float srel[4][16][4];
  __shared__ float sbias[4][16][4];
  __shared__ float red[4][16*68];
  int tid = threadIdx.x;
  int bn0 = blockIdx.x * 4;
  int b   = bn0 >> 12;               // 4096 % 4 == 0 -> all 4 points share b
  sw1[tid] = w1f[tid];
  sw2[tid] = W2t[tid];
  if (tid < 64) {
    int p = tid >> 4, kk = tid & 15;
    int bn = bn0 + p, n = bn & 4095;
    int j = idx[bn*16 + kk];
    sidx[p][kk] = j;
    const float* pb = xyz + (size_t)b * 3 * NPT;
    srel[p][kk][0] = pb[j]         - pb[n];
    srel[p][kk][1] = pb[NPT + j]   - pb[NPT + n];
    srel[p][kk][2] = pb[2*NPT + j] - pb[2*NPT + n];
  }
  __syncthreads();
  {  // ---- bias phase: 4 points per weight read ----
    int kk = tid >> 4, cs = tid & 15;
    float rx[4], ry[4], rz[4], h[4][4];
#pragma unroll
    for (int p = 0; p < 4; p++) {
      rx[p] = srel[p][kk][0]; ry[p] = srel[p][kk][1]; rz[p] = srel[p][kk][2];
#pragma unroll
      for (int q = 0; q < 4; q++) h[p][q] = 0.f;
    }
#pragma unroll
    for (int i = 0; i < 16; i++) {
      int c = cs*16 + ((i + cs) & 15);        // staggered -> 2-way-free banks
      float4 w  = sw1[c];
      float4 w2 = sw2[c];
#pragma unroll
      for (int p = 0; p < 4; p++) {
        float t0 = fmaxf(fmaf(rx[p], w.x, fmaf(ry[p], w.y, fmaf(rz[p], w.z, w.w))), 0.f);
        h[p][0] = fmaf(t0, w2.x, h[p][0]); h[p][1] = fmaf(t0, w2.y, h[p][1]);
        h[p][2] = fmaf(t0, w2.z, h[p][2]); h[p][3] = fmaf(t0, w2.w, h[p][3]);
      }
    }
#pragma unroll
    for (int off = 1; off < 16; off <<= 1)
#pragma unroll
      for (int p = 0; p < 4; p++)
#pragma unroll
        for (int q = 0; q < 4; q++)
          h[p][q] += __shfl_xor(h[p][q], off, 64);
    if (cs == 0)
#pragma unroll
      for (int p = 0; p < 4; p++)
#pragma unroll
        for (int q = 0; q < 4; q++) sbias[p][kk][q] = h[p][q];
  }
  __syncthreads();
  // ---- attention phase: 4 points serial ----
  int wv   = tid >> 6;              // head
  int lane = tid & 63;
  int k    = lane >> 2;             // neighbor
  int c4   = lane & 3;              // channel chunk
  int ch0  = wv*64 + c4*16;
  size_t base = (size_t)(b*NPT) * 768;
#pragma unroll 1
  for (int p = 0; p < 4; p++) {
    int bn = bn0 + p;
    size_t rowq = (size_t)bn * 768;
    float qf[16];
    {
      uint4 q0 = *(const uint4*)(qkv + rowq + ch0);
      uint4 q1 = *(const uint4*)(qkv + rowq + ch0 + 8);
      up16(q0, q1, qf);
    }
    int j = sidx[p][k];
    float dot = 0.f;
    {
      const unsigned short* krow = qkv + base + (size_t)j*768 + 256 + ch0;
      uint4 k0 = *(const uint4*)(krow);
      uint4 k1 = *(const uint4*)(krow + 8);
      float kf[16];
      up16(k0, k1, kf);
#pragma unroll
      for (int i = 0; i < 16; i++) dot = fmaf(qf[i], kf[i], dot);
    }
    dot += __shfl_xor(dot, 1, 64);
    dot += __shfl_xor(dot, 2, 64);
    float logit = dot * 0.125f + sbias[p][k][wv];
    float mx = logit;
#pragma unroll
    for (int off = 4; off < 64; off <<= 1) mx = fmaxf(mx, __shfl_xor(mx, off, 64));
    float e = __expf(logit - mx);
    float ssum = e;
#pragma unroll
    for (int off = 4; off < 64; off <<= 1) ssum += __shfl_xor(ssum, off, 64);
    float w = e / ssum;
    {
      const unsigned short* vrow = qkv + base + (size_t)j*768 + 512 + ch0;
      uint4 v0 = *(const uint4*)(vrow);
      uint4 v1 = *(const uint4*)(vrow + 8);
      float vf[16];
      up16(v0, v1, vf);
      float* dst = &red[wv][k*68 + c4*16];
#pragma unroll
      for (int g = 0; g < 4; g++)
        ((float4*)dst)[g] = make_float4(w*vf[g*4], w*vf[g*4+1], w*vf[g*4+2], w*vf[g*4+3]);
    }
    __syncthreads();
    float o = 0.f;
#pragma unroll
    for (int kk2 = 0; kk2 < 16; kk2++) o += red[wv][kk2*68 + lane];
    attn_b[(size_t)bn*256 + wv*64 + lane] = f2b(o);
    __syncthreads();
  }
}

extern "C" void kernel_launch(void* const* d_in, const int* in_sizes, int n_in,
                              void* d_out, int out_size, void* d_ws, size_t ws_size,
                              hipStream_t stream) {
  const float* x     = (const float*)d_in[0];
  const float* xyz   = (const float*)d_in[1];
  const float* Wq    = (const float*)d_in[2];
  const float* Wkv   = (const float*)d_in[3];
  const float* Wproj = (const float*)d_in[4];
  const float* rp_w1 = (const float*)d_in[5];
  const float* rp_g  = (const float*)d_in[6];
  const float* rp_b  = (const float*)d_in[7];
  const float* rp_m  = (const float*)d_in[8];
  const float* rp_v  = (const float*)d_in[9];
  const float* rp_w2 = (const float*)d_in[10];
  const float* bn1_g = (const float*)d_in[11];
  const float* bn1_b = (const float*)d_in[12];
  const float* bn1_m = (const float*)d_in[13];
  const float* bn1_v = (const float*)d_in[14];
  const float* bn2_g = (const float*)d_in[15];
  const float* bn2_b = (const float*)d_in[16];
  const float* bn2_m = (const float*)d_in[17];
  const float* bn2_v = (const float*)d_in[18];
  const float* ffn_w1 = (const float*)d_in[19];
  const float* ffn_b1 = (const float*)d_in[20];
  const float* ffn_w2 = (const float*)d_in[21];
  const float* ffn_b2 = (const float*)d_in[22];

  char* ws = (char*)d_ws;
  // static region
  float4* w1f = (float4*)(ws + 0);                         //   4 KB
  float4* W2t = (float4*)(ws + 4096);                      //   4 KB
  int*    idx = (int*)  (ws + 8192);                       // 512 KB
  // reuse region A (32 MB): KNN scratch first, then post-attn tensors
  const size_t oA = 532480;
  float4*         Pp     = (float4*)(ws + oA);             // 32 MB [B*N][512] (d,idx)
  unsigned short* attn_b = (unsigned short*)(ws + oA);                 //  4 MB bf16 [B][N][256]
  float*          x1f    = (float*)(ws + oA + (4u<<20));               //  8 MB fp32 [B][N][256]
  unsigned short* x1b    = (unsigned short*)(ws + oA + (12u<<20));     //  4 MB bf16 [B][N][256]
  unsigned short* h_b    = (unsigned short*)(ws + oA + (16u<<20));     // 16 MB bf16 [B][N][1024]
  // region B: weights + casted x + qkv
  const size_t oB = oA + (32u<<20);
  unsigned short* Wqkv_b  = (unsigned short*)(ws + oB);                // 384 KB [768][256]
  unsigned short* Wproj_b = (unsigned short*)(ws + oB + 393216);       // 128 KB
  unsigned short* W1_b    = (unsigned short*)(ws + oB + 524288);       // 512 KB
  unsigned short* W2_b    = (unsigned short*)(ws + oB + 1048576);      // 512 KB
  unsigned short* xb      = (unsigned short*)(ws + oB + 1572864);      //   4 MB bf16 [B][N][256]
  float*          xf      = (float*)(ws + oB + 1572864 + (4u<<20));    //   8 MB fp32 [B][N][256]
  unsigned short* qkv     = (unsigned short*)(ws + oB + 1572864 + (12u<<20)); // 12 MB bf16 [B][N][768]

  stage1_kernel<<<4609, 256, 0, stream>>>(x, xb, xf, xyz, Pp,
                                          Wq, Wkv, Wproj, ffn_w1, ffn_w2,
                                          Wqkv_b, Wproj_b, W1_b, W2_b,
                                          rp_w1, rp_g, rp_b, rp_m, rp_v, rp_w2,
                                          w1f, W2t);

  MG pqkv = {xb, Wqkv_b, 256, 768, qkv, nullptr,
             nullptr, nullptr, nullptr, nullptr, nullptr, nullptr};
  stage2_kernel<<<2816, 256, 0, stream>>>(Pp, idx, pqkv);

  attn_kernel<<<(BB*NPT)/4, 256, 0, stream>>>(qkv, w1f, W2t, xyz, idx, attn_b);

  MG pproj = {attn_b, Wproj_b, 256, 256, x1b, x1f,
              nullptr, xf, bn1_g, bn1_b, bn1_m, bn1_v};
  mgemm_kernel<2><<<dim3(32, 4, BB), 256, 0, stream>>>(pproj);

  MG pf1 = {x1b, W1_b, 256, 1024, h_b, nullptr,
            ffn_b1, nullptr, nullptr, nullptr, nullptr, nullptr};
  mgemm_kernel<1><<<dim3(32, 16, BB), 256, 0, stream>>>(pf1);

  MG pf2 = {h_b, W2_b, 1024, 256, nullptr, (float*)d_out,
            ffn_b2, x1f, bn2_g, bn2_b, bn2_m, bn2_v};
  mgemm_kernel<3><<<dim3(32, 4, BB), 256, 0, stream>>>(pf2);
}

// Round 14
// 249.948 us; speedup vs baseline: 1.1277x; 1.0191x over previous
//
#include <hip/hip_runtime.h>
#include <math.h>

#define BB   2
#define CC   256
#define NPT  4096
#define HH   4
#define DD   64
#define KNN  16
#define EPSBN 1e-5f

typedef __attribute__((ext_vector_type(8))) short short8;
typedef __attribute__((ext_vector_type(4))) float f32x4;

typedef __attribute__((address_space(3))) unsigned int lds_u32;
typedef const __attribute__((address_space(1))) unsigned int glb_u32;
__device__ __forceinline__ void gl_lds16(const void* g, void* l) {
  __builtin_amdgcn_global_load_lds((glb_u32*)g, (lds_u32*)l, 16, 0, 0);
}

__device__ __forceinline__ unsigned short f2b(float f) {
  union { float f; unsigned int u; } v; v.f = f;
  unsigned int r = (v.u + 0x7FFFu + ((v.u >> 16) & 1u)) >> 16;
  return (unsigned short)r;
}
__device__ __forceinline__ void up2(unsigned int u, float& a, float& b) {
  union { unsigned int x; float f; } lo, hi;
  lo.x = u << 16; hi.x = u & 0xffff0000u;
  a = lo.f; b = hi.f;
}
__device__ __forceinline__ void up16(uint4 u0, uint4 u1, float* f) {
  up2(u0.x, f[0], f[1]);  up2(u0.y, f[2], f[3]);
  up2(u0.z, f[4], f[5]);  up2(u0.w, f[6], f[7]);
  up2(u1.x, f[8], f[9]);  up2(u1.y, f[10], f[11]);
  up2(u1.z, f[12], f[13]); up2(u1.w, f[14], f[15]);
}

// ================= stage 1 bodies (independent work, fused dispatch) =================
__device__ __forceinline__
void wcast_body(const float* Wq, const float* Wkv, const float* Wp,
                const float* W1, const float* W2,
                unsigned short* oQKV, unsigned short* oP,
                unsigned short* o1, unsigned short* o2,
                const float* rp_w1, const float* rp_g, const float* rp_b,
                const float* rp_m, const float* rp_v, const float* rp_w2,
                float4* w1f, float4* W2t, int blk) {
  if (blk == 3072) {            // prep: fold rp BN into w1, reduce rp_w2 over heads
    int c = threadIdx.x;
    float s  = rp_g[c] / sqrtf(rp_v[c] + EPSBN);
    float b0 = rp_b[c] - rp_m[c] * s;
    w1f[c] = make_float4(rp_w1[c*3+0]*s, rp_w1[c*3+1]*s, rp_w1[c*3+2]*s, b0);
    float a0=0.f,a1=0.f,a2=0.f,a3=0.f;
    for (int o = 0; o < 64; o++) {
      a0 += rp_w2[(      o)*CC + c];
      a1 += rp_w2[( 64 + o)*CC + c];
      a2 += rp_w2[(128 + o)*CC + c];
      a3 += rp_w2[(192 + o)*CC + c];
    }
    W2t[c] = make_float4(a0,a1,a2,a3);
    return;
  }
  int i = blk * 256 + threadIdx.x;          // 786432 total
  if (i < 65536)        oQKV[i] = f2b(Wq[i]);
  else if (i < 196608)  oQKV[i] = f2b(Wkv[i - 65536]);
  else if (i < 262144)  oP[i - 196608] = f2b(Wp[i - 196608]);
  else if (i < 524288)  o1[i - 262144] = f2b(W1[i - 262144]);
  else                  o2[i - 524288] = f2b(W2[i - 524288]);
}

__device__ __forceinline__
void xcast_body(const float* x, unsigned short* xb, float* xf,
                int bx, int by, int bz) {
  __shared__ float T[64][65];
  int n0 = bx * 64, c0 = by * 64, bb = bz;
  int tid = threadIdx.x;
  {
    int crow = tid >> 2, ns = (tid & 3) * 16;
    const float* xp = x + ((size_t)(bb*CC + c0 + crow))*NPT + n0 + ns;
#pragma unroll
    for (int i = 0; i < 4; i++) {
      float4 v = ((const float4*)xp)[i];
      T[crow][ns + i*4 + 0] = v.x; T[crow][ns + i*4 + 1] = v.y;
      T[crow][ns + i*4 + 2] = v.z; T[crow][ns + i*4 + 3] = v.w;
    }
  }
  __syncthreads();
  {
    int nrow = tid >> 2, cs = (tid & 3) * 16;
    float vals[16];
#pragma unroll
    for (int i = 0; i < 16; i++) vals[i] = T[cs + i][nrow];
    size_t orow = ((size_t)(bb*NPT + n0 + nrow))*CC + c0 + cs;
#pragma unroll
    for (int i = 0; i < 4; i++)
      *(float4*)&xf[orow + i*4] = make_float4(vals[i*4], vals[i*4+1], vals[i*4+2], vals[i*4+3]);
    unsigned short us[16];
#pragma unroll
    for (int i = 0; i < 16; i++) us[i] = f2b(vals[i]);
    *(uint4*)&xb[orow]     = *(const uint4*)&us[0];
    *(uint4*)&xb[orow + 8] = *(const uint4*)&us[8];
  }
}

// KNN stage 1 (R9 plateau + unroll-2): packed-u32 min/max sorted-insert network
#define MSTEP(K) { unsigned int t = min(key, K); key = max(key, K); K = t; }
#define MPROC(M4, MI) { \
    float nd = fmaf(qx2, (M4).x, fmaf(qy2, (M4).y, fmaf(qz2, (M4).z, (M4).w + qsq))); \
    nd = fmaxf(nd, 0.f); \
    unsigned int key = (__float_as_uint(nd) & 0xFFFFFE00u) | (unsigned int)(MI); \
    MSTEP(k0)  MSTEP(k1)  MSTEP(k2)  MSTEP(k3) \
    MSTEP(k4)  MSTEP(k5)  MSTEP(k6)  MSTEP(k7) \
    MSTEP(k8)  MSTEP(k9)  MSTEP(k10) MSTEP(k11) \
    MSTEP(k12) MSTEP(k13) MSTEP(k14) MSTEP(k15) }
__device__ __forceinline__
void knn_partial_body(const float* xyz, float4* Pp, int s, int qg, int b) {
  __shared__ float4 sp[512];    // (x, y, z, |p|^2)
  const float* base = xyz + (size_t)b * 3 * NPT;
  int c0 = s * 512;
  for (int i = threadIdx.x; i < 512; i += 256) {
    float mx = base[c0 + i], my = base[NPT + c0 + i], mz = base[2*NPT + c0 + i];
    sp[i] = make_float4(mx, my, mz, mx*mx + my*my + mz*mz);
  }
  int lane = threadIdx.x & 63;
  int wv   = threadIdx.x >> 6;
  int qn   = qg * 64 + lane;
  float qx = base[qn], qy = base[NPT + qn], qz = base[2*NPT + qn];
  float qsq = qx*qx + qy*qy + qz*qz;
  float qx2 = -2.f*qx, qy2 = -2.f*qy, qz2 = -2.f*qz;
  __syncthreads();

  unsigned int k0=0xFFFFFFFFu,k1=0xFFFFFFFFu,k2=0xFFFFFFFFu,k3=0xFFFFFFFFu,
               k4=0xFFFFFFFFu,k5=0xFFFFFFFFu,k6=0xFFFFFFFFu,k7=0xFFFFFFFFu,
               k8=0xFFFFFFFFu,k9=0xFFFFFFFFu,k10=0xFFFFFFFFu,k11=0xFFFFFFFFu,
               k12=0xFFFFFFFFu,k13=0xFFFFFFFFu,k14=0xFFFFFFFFu,k15=0xFFFFFFFFu;

  int mbase = wv * 128;
#pragma unroll 2
  for (int mm = 0; mm < 128; mm += 4) {
    int m = mbase + mm;
    float4 a = sp[m], bq = sp[m+1], cq = sp[m+2], dq = sp[m+3];
    MPROC(a,  m)
    MPROC(bq, m+1)
    MPROC(cq, m+2)
    MPROC(dq, m+3)
  }

  int gq = b * NPT + qn;
  float4* out = Pp + (size_t)gq * 256 + (s*4 + wv)*8;
#define UNP(K) __uint_as_float(K & 0xFFFFFE00u), __int_as_float(c0 + (int)(K & 0x1FFu))
  out[0] = make_float4(UNP(k0),  UNP(k1));
  out[1] = make_float4(UNP(k2),  UNP(k3));
  out[2] = make_float4(UNP(k4),  UNP(k5));
  out[3] = make_float4(UNP(k6),  UNP(k7));
  out[4] = make_float4(UNP(k8),  UNP(k9));
  out[5] = make_float4(UNP(k10), UNP(k11));
  out[6] = make_float4(UNP(k12), UNP(k13));
  out[7] = make_float4(UNP(k14), UNP(k15));
#undef UNP
}

// stage1 fused dispatch: [0,512) xcast | [512,3585) wcast | [3585,4609) knn_partial.
__global__ __launch_bounds__(256) __attribute__((amdgpu_waves_per_eu(1, 4)))
void stage1_kernel(const float* x, unsigned short* xb, float* xf,
                   const float* xyz, float4* Pp,
                   const float* Wq, const float* Wkv, const float* Wp,
                   const float* W1, const float* W2,
                   unsigned short* oQKV, unsigned short* oP,
                   unsigned short* o1, unsigned short* o2,
                   const float* rp_w1, const float* rp_g, const float* rp_b,
                   const float* rp_m, const float* rp_v, const float* rp_w2,
                   float4* w1f, float4* W2t) {
  int bi = blockIdx.x;
  if (bi < 512) {
    xcast_body(x, xb, xf, bi & 63, (bi >> 6) & 3, bi >> 8);
  } else if (bi < 3585) {
    wcast_body(Wq, Wkv, Wp, W1, W2, oQKV, oP, o1, o2,
               rp_w1, rp_g, rp_b, rp_m, rp_v, rp_w2, w1f, W2t, bi - 512);
  } else {
    int i = bi - 3585;
    knn_partial_body(xyz, Pp, i & 7, (i >> 3) & 63, i >> 9);
  }
}

// ================= stage 2: knn_merge + qkv GEMM (independent, fused) ================
__device__ __forceinline__
void knn_merge_body(const float4* Pp, int* idx_out, int blk) {
  int wv   = threadIdx.x >> 6;
  int lane = threadIdx.x & 63;
  int gq   = blk * 4 + wv;
  float d[8]; int ii[8];
  const float4* base = Pp + (size_t)gq * 256;
#pragma unroll
  for (int j = 0; j < 4; j++) {
    float4 v = base[j*64 + lane];
    d[2*j+0] = v.x; ii[2*j+0] = __float_as_int(v.y);
    d[2*j+1] = v.z; ii[2*j+1] = __float_as_int(v.w);
  }
  for (int sel = 0; sel < 16; sel++) {
    float bd = 3.5e38f; int bi = 0x7fffffff;
#pragma unroll
    for (int t = 0; t < 8; t++) {
      bool better = (d[t] < bd) || (d[t] == bd && ii[t] < bi);
      if (better) { bd = d[t]; bi = ii[t]; }
    }
#pragma unroll
    for (int off = 1; off < 64; off <<= 1) {
      float od = __shfl_xor(bd, off, 64);
      int   oi = __shfl_xor(bi, off, 64);
      if (od < bd || (od == bd && oi < bi)) { bd = od; bi = oi; }
    }
#pragma unroll
    for (int t = 0; t < 8; t++)
      if (ii[t] == bi) d[t] = 3.5e38f;
    if (lane == 0) idx_out[gq*16 + sel] = bi;
  }
}

// ------- MFMA bf16 GEMM v3: NT-templated N-tile (NT*64 rows) ------------------------
// NT=2: 128n tile (16 MFMA/barrier) for well-occupied GEMMs (qkv 3/CU, ffn1 4/CU).
// NT=1: 64n tile for proj/ffn2 -> 512 blocks = 2 blocks/CU so co-resident blocks
// cover each other's global_load_lds barrier drains (R13: at 1 block/CU the ~900cy
// DMA drain per chunk is fully exposed; m114 wave-overlap needs >=2 blocks).
struct MG {
  const unsigned short* A; const unsigned short* Wt; int K; int M;
  unsigned short* OutB; float* OutF;
  const float* bias; const float* resid;
  const float* bng; const float* bnb; const float* bnm; const float* bnv;
};

template<int EPI, int NT>
__device__ __forceinline__ void mgemm_body(const MG& p, int bx, int by, int bz) {
  __shared__ unsigned short As[NT*64*64];
  __shared__ unsigned short Bs[64*64];
  const int tid  = threadIdx.x;
  const int bb   = bz;
  const int n0   = bx * (NT*64);
  const int m0   = by * 64;
  const int lane = tid & 63;
  const int wv   = tid >> 6;
  const int l15  = lane & 15;
  const int quad = lane >> 4;
  const int K    = p.K;
  const int WR   = NT*16;                   // wave row span

  f32x4 acc[NT][4];
#pragma unroll
  for (int i = 0; i < NT; i++)
#pragma unroll
    for (int j = 0; j < 4; j++) acc[i][j] = (f32x4){0.f, 0.f, 0.f, 0.f};

  const int srow = wv*8 + (lane >> 3);
  const int pseg = lane & 7;
  const unsigned short* Abase = p.A  + (size_t)bb*NPT*K;

  for (int c0 = 0; c0 < K; c0 += 64) {
#pragma unroll
    for (int t = 0; t < NT*2; t++) {
      int row = t*32 + srow;
      int ls  = pseg ^ (row & 7);
      gl_lds16(Abase + (size_t)(n0 + row)*K + c0 + ls*8,
               &As[wv*512 + t*2048 + lane*8]);
    }
#pragma unroll
    for (int t = 0; t < 2; t++) {
      int row = t*32 + srow;
      int ls  = pseg ^ (row & 7);
      gl_lds16(p.Wt + (size_t)(m0 + row)*K + c0 + ls*8,
               &Bs[wv*512 + t*2048 + lane*8]);
    }
    __syncthreads();
    short8 bf[4][2];
#pragma unroll
    for (int mt = 0; mt < 4; mt++)
#pragma unroll
      for (int kk = 0; kk < 2; kk++) {
        int row = mt*16 + l15;
        int ps  = (kk*4 + quad) ^ (row & 7);
        bf[mt][kk] = *(const short8*)&Bs[row*64 + ps*8];
      }
#pragma unroll
    for (int nt = 0; nt < NT; nt++)
#pragma unroll
      for (int kk = 0; kk < 2; kk++) {
        int row = wv*WR + nt*16 + l15;
        int ps  = (kk*4 + quad) ^ (row & 7);
        short8 af = *(const short8*)&As[row*64 + ps*8];
#pragma unroll
        for (int mt = 0; mt < 4; mt++)
          acc[nt][mt] = __builtin_amdgcn_mfma_f32_16x16x32_bf16(af, bf[mt][kk], acc[nt][mt], 0, 0, 0);
      }
    __syncthreads();
  }

  if (EPI == 0 || EPI == 1) {
    float bs[4];
#pragma unroll
    for (int mt = 0; mt < 4; mt++)
      bs[mt] = (EPI == 1) ? p.bias[m0 + mt*16 + l15] : 0.f;
#pragma unroll
    for (int nt = 0; nt < NT; nt++)
#pragma unroll
      for (int reg = 0; reg < 4; reg++) {
        size_t row = ((size_t)(bb*NPT + n0 + wv*WR + nt*16 + quad*4 + reg))*p.M + m0;
#pragma unroll
        for (int mt = 0; mt < 4; mt++) {
          float v = acc[nt][mt][reg] + bs[mt];
          if (EPI == 1) v = fmaxf(v, 0.f);
          p.OutB[row + mt*16 + l15] = f2b(v);
        }
      }
  } else if (EPI == 2) {
    float sc[4], sh[4];
#pragma unroll
    for (int mt = 0; mt < 4; mt++) {
      int m = m0 + mt*16 + l15;
      float s = p.bng[m] / sqrtf(p.bnv[m] + EPSBN);
      sc[mt] = s; sh[mt] = p.bnb[m] - p.bnm[m]*s;
    }
#pragma unroll
    for (int nt = 0; nt < NT; nt++)
#pragma unroll
      for (int reg = 0; reg < 4; reg++) {
        size_t row = ((size_t)(bb*NPT + n0 + wv*WR + nt*16 + quad*4 + reg))*p.M + m0;
#pragma unroll
        for (int mt = 0; mt < 4; mt++) {
          float r = p.resid[row + mt*16 + l15];
          float v = (acc[nt][mt][reg] + r)*sc[mt] + sh[mt];
          p.OutF[row + mt*16 + l15] = v;
          p.OutB[row + mt*16 + l15] = f2b(v);
        }
      }
  } else {  // EPI == 3
    __shared__ float Tb[4][4][16*17];
    float sc[4], sh[4], bs[4];
#pragma unroll
    for (int mt = 0; mt < 4; mt++) {
      int m = m0 + mt*16 + l15;
      float s = p.bng[m] / sqrtf(p.bnv[m] + EPSBN);
      sc[mt] = s; sh[mt] = p.bnb[m] - p.bnm[m]*s;
      bs[mt] = p.bias[m];
    }
#pragma unroll
    for (int nt = 0; nt < NT; nt++) {
#pragma unroll
      for (int reg = 0; reg < 4; reg++) {
        size_t row = ((size_t)(bb*NPT + n0 + wv*WR + nt*16 + quad*4 + reg))*p.M + m0;
#pragma unroll
        for (int mt = 0; mt < 4; mt++) {
          float r = p.resid[row + mt*16 + l15];
          float v = (acc[nt][mt][reg] + bs[mt] + r)*sc[mt] + sh[mt];
          Tb[wv][mt][(quad*4 + reg)*17 + l15] = v;
        }
      }
      __syncthreads();
#pragma unroll
      for (int mt = 0; mt < 4; mt++)
#pragma unroll
        for (int reg = 0; reg < 4; reg++) {
          float v = Tb[wv][mt][l15*17 + quad*4 + reg];
          p.OutF[((size_t)(bb*p.M + m0 + mt*16 + quad*4 + reg))*NPT
                 + n0 + wv*WR + nt*16 + l15] = v;
        }
      __syncthreads();
    }
  }
}

template<int EPI, int NT>
__global__ __launch_bounds__(256)
void mgemm_kernel(MG p) { mgemm_body<EPI, NT>(p, blockIdx.x, blockIdx.y, blockIdx.z); }

// stage2 fused: [0,2048) knn_merge | [2048,2816) qkv GEMM (grid 32x12x2 linearized)
__global__ __launch_bounds__(256)
void stage2_kernel(const float4* Pp, int* idx, MG pqkv) {
  int bi = blockIdx.x;
  if (bi < 2048) {
    knn_merge_body(Pp, idx, bi);
  } else {
    int i = bi - 2048;
    mgemm_body<0, 2>(pqkv, i & 31, (i >> 5) % 12, i / 384);
  }
}

// ---------------- fused attention v4: 4 points/block, shared weight reads ----------
__global__ __launch_bounds__(256, 4)
void attn_kernel(const unsigned short* __restrict__ qkv, const float4* __restrict__ w1f,
                 const float4* __restrict__ W2t, const float* __restrict__ xyz,
                 const int* __restrict__ idx, unsigned short* __restrict__ attn_b) {
  __shared__ float4 sw1[256];
  __shared__ float4 sw2[256];
  __shared__ int   sidx[4][16];
  __shared__ float srel[4][16][4];
  __shared__ float sbias[4][16][4];
  __shared__ float red[4][16*68];
  int tid = threadIdx.x;
  int bn0 = blockIdx.x * 4;
  int b   = bn0 >> 12;
  sw1[tid] = w1f[tid];
  sw2[tid] = W2t[tid];
  if (tid < 64) {
    int p = tid >> 4, kk = tid & 15;
    int bn = bn0 + p, n = bn & 4095;
    int j = idx[bn*16 + kk];
    sidx[p][kk] = j;
    const float* pb = xyz + (size_t)b * 3 * NPT;
    srel[p][kk][0] = pb[j]         - pb[n];
    srel[p][kk][1] = pb[NPT + j]   - pb[NPT + n];
    srel[p][kk][2] = pb[2*NPT + j] - pb[2*NPT + n];
  }
  __syncthreads();
  {  // ---- bias phase: 4 points per weight read ----
    int kk = tid >> 4, cs = tid & 15;
    float rx[4], ry[4], rz[4], h[4][4];
#pragma unroll
    for (int p = 0; p < 4; p++) {
      rx[p] = srel[p][kk][0]; ry[p] = srel[p][kk][1]; rz[p] = srel[p][kk][2];
#pragma unroll
      for (int q = 0; q < 4; q++) h[p][q] = 0.f;
    }
#pragma unroll
    for (int i = 0; i < 16; i++) {
      int c = cs*16 + ((i + cs) & 15);
      float4 w  = sw1[c];
      float4 w2 = sw2[c];
#pragma unroll
      for (int p = 0; p < 4; p++) {
        float t0 = fmaxf(fmaf(rx[p], w.x, fmaf(ry[p], w.y, fmaf(rz[p], w.z, w.w))), 0.f);
        h[p][0] = fmaf(t0, w2.x, h[p][0]); h[p][1] = fmaf(t0, w2.y, h[p][1]);
        h[p][2] = fmaf(t0, w2.z, h[p][2]); h[p][3] = fmaf(t0, w2.w, h[p][3]);
      }
    }
#pragma unroll
    for (int off = 1; off < 16; off <<= 1)
#pragma unroll
      for (int p = 0; p < 4; p++)
#pragma unroll
        for (int q = 0; q < 4; q++)
          h[p][q] += __shfl_xor(h[p][q], off, 64);
    if (cs == 0)
#pragma unroll
      for (int p = 0; p < 4; p++)
#pragma unroll
        for (int q = 0; q < 4; q++) sbias[p][kk][q] = h[p][q];
  }
  __syncthreads();
  // ---- attention phase: 4 points serial ----
  int wv   = tid >> 6;
  int lane = tid & 63;
  int k    = lane >> 2;
  int c4   = lane & 3;
  int ch0  = wv*64 + c4*16;
  size_t base = (size_t)(b*NPT) * 768;
#pragma unroll 1
  for (int p = 0; p < 4; p++) {
    int bn = bn0 + p;
    size_t rowq = (size_t)bn * 768;
    float qf[16];
    {
      uint4 q0 = *(const uint4*)(qkv + rowq + ch0);
      uint4 q1 = *(const uint4*)(qkv + rowq + ch0 + 8);
      up16(q0, q1, qf);
    }
    int j = sidx[p][k];
    float dot = 0.f;
    {
      const unsigned short* krow = qkv + base + (size_t)j*768 + 256 + ch0;
      uint4 k0 = *(const uint4*)(krow);
      uint4 k1 = *(const uint4*)(krow + 8);
      float kf[16];
      up16(k0, k1, kf);
#pragma unroll
      for (int i = 0; i < 16; i++) dot = fmaf(qf[i], kf[i], dot);
    }
    dot += __shfl_xor(dot, 1, 64);
    dot += __shfl_xor(dot, 2, 64);
    float logit = dot * 0.125f + sbias[p][k][wv];
    float mx = logit;
#pragma unroll
    for (int off = 4; off < 64; off <<= 1) mx = fmaxf(mx, __shfl_xor(mx, off, 64));
    float e = __expf(logit - mx);
    float ssum = e;
#pragma unroll
    for (int off = 4; off < 64; off <<= 1) ssum += __shfl_xor(ssum, off, 64);
    float w = e / ssum;
    {
      const unsigned short* vrow = qkv + base + (size_t)j*768 + 512 + ch0;
      uint4 v0 = *(const uint4*)(vrow);
      uint4 v1 = *(const uint4*)(vrow + 8);
      float vf[16];
      up16(v0, v1, vf);
      float* dst = &red[wv][k*68 + c4*16];
#pragma unroll
      for (int g = 0; g < 4; g++)
        ((float4*)dst)[g] = make_float4(w*vf[g*4], w*vf[g*4+1], w*vf[g*4+2], w*vf[g*4+3]);
    }
    __syncthreads();
    float o = 0.f;
#pragma unroll
    for (int kk2 = 0; kk2 < 16; kk2++) o += red[wv][kk2*68 + lane];
    attn_b[(size_t)bn*256 + wv*64 + lane] = f2b(o);
    __syncthreads();
  }
}

extern "C" void kernel_launch(void* const* d_in, const int* in_sizes, int n_in,
                              void* d_out, int out_size, void* d_ws, size_t ws_size,
                              hipStream_t stream) {
  const float* x     = (const float*)d_in[0];
  const float* xyz   = (const float*)d_in[1];
  const float* Wq    = (const float*)d_in[2];
  const float* Wkv   = (const float*)d_in[3];
  const float* Wproj = (const float*)d_in[4];
  const float* rp_w1 = (const float*)d_in[5];
  const float* rp_g  = (const float*)d_in[6];
  const float* rp_b  = (const float*)d_in[7];
  const float* rp_m  = (const float*)d_in[8];
  const float* rp_v  = (const float*)d_in[9];
  const float* rp_w2 = (const float*)d_in[10];
  const float* bn1_g = (const float*)d_in[11];
  const float* bn1_b = (const float*)d_in[12];
  const float* bn1_m = (const float*)d_in[13];
  const float* bn1_v = (const float*)d_in[14];
  const float* bn2_g = (const float*)d_in[15];
  const float* bn2_b = (const float*)d_in[16];
  const float* bn2_m = (const float*)d_in[17];
  const float* bn2_v = (const float*)d_in[18];
  const float* ffn_w1 = (const float*)d_in[19];
  const float* ffn_b1 = (const float*)d_in[20];
  const float* ffn_w2 = (const float*)d_in[21];
  const float* ffn_b2 = (const float*)d_in[22];

  char* ws = (char*)d_ws;
  // static region
  float4* w1f = (float4*)(ws + 0);                         //   4 KB
  float4* W2t = (float4*)(ws + 4096);                      //   4 KB
  int*    idx = (int*)  (ws + 8192);                       // 512 KB
  // reuse region A (32 MB): KNN scratch first, then post-attn tensors
  const size_t oA = 532480;
  float4*         Pp     = (float4*)(ws + oA);             // 32 MB [B*N][512] (d,idx)
  unsigned short* attn_b = (unsigned short*)(ws + oA);                 //  4 MB bf16 [B][N][256]
  float*          x1f    = (float*)(ws + oA + (4u<<20));               //  8 MB fp32 [B][N][256]
  unsigned short* x1b    = (unsigned short*)(ws + oA + (12u<<20));     //  4 MB bf16 [B][N][256]
  unsigned short* h_b    = (unsigned short*)(ws + oA + (16u<<20));     // 16 MB bf16 [B][N][1024]
  // region B: weights + casted x + qkv
  const size_t oB = oA + (32u<<20);
  unsigned short* Wqkv_b  = (unsigned short*)(ws + oB);                // 384 KB [768][256]
  unsigned short* Wproj_b = (unsigned short*)(ws + oB + 393216);       // 128 KB
  unsigned short* W1_b    = (unsigned short*)(ws + oB + 524288);       // 512 KB
  unsigned short* W2_b    = (unsigned short*)(ws + oB + 1048576);      // 512 KB
  unsigned short* xb      = (unsigned short*)(ws + oB + 1572864);      //   4 MB bf16 [B][N][256]
  float*          xf      = (float*)(ws + oB + 1572864 + (4u<<20));    //   8 MB fp32 [B][N][256]
  unsigned short* qkv     = (unsigned short*)(ws + oB + 1572864 + (12u<<20)); // 12 MB bf16 [B][N][768]

  stage1_kernel<<<4609, 256, 0, stream>>>(x, xb, xf, xyz, Pp,
                                          Wq, Wkv, Wproj, ffn_w1, ffn_w2,
                                          Wqkv_b, Wproj_b, W1_b, W2_b,
                                          rp_w1, rp_g, rp_b, rp_m, rp_v, rp_w2,
                                          w1f, W2t);

  MG pqkv = {xb, Wqkv_b, 256, 768, qkv, nullptr,
             nullptr, nullptr, nullptr, nullptr, nullptr, nullptr};
  stage2_kernel<<<2816, 256, 0, stream>>>(Pp, idx, pqkv);

  attn_kernel<<<(BB*NPT)/4, 256, 0, stream>>>(qkv, w1f, W2t, xyz, idx, attn_b);

  MG pproj = {attn_b, Wproj_b, 256, 256, x1b, x1f,
              nullptr, xf, bn1_g, bn1_b, bn1_m, bn1_v};
  mgemm_kernel<2, 1><<<dim3(64, 4, BB), 256, 0, stream>>>(pproj);

  MG pf1 = {x1b, W1_b, 256, 1024, h_b, nullptr,
            ffn_b1, nullptr, nullptr, nullptr, nullptr, nullptr};
  mgemm_kernel<1, 2><<<dim3(32, 16, BB), 256, 0, stream>>>(pf1);

  MG pf2 = {h_b, W2_b, 1024, 256, nullptr, (float*)d_out,
            ffn_b2, x1f, bn2_g, bn2_b, bn2_m, bn2_v};
  mgemm_kernel<3, 1><<<dim3(64, 4, BB), 256, 0, stream>>>(pf2);
}

// Round 15
// 249.775 us; speedup vs baseline: 1.1285x; 1.0007x over previous
//
#include <hip/hip_runtime.h>
#include <math.h>

#define BB   2
#define CC   256
#define NPT  4096
#define HH   4
#define DD   64
#define KNN  16
#define EPSBN 1e-5f

typedef __attribute__((ext_vector_type(8))) short short8;
typedef __attribute__((ext_vector_type(4))) float f32x4;

typedef __attribute__((address_space(3))) unsigned int lds_u32;
typedef const __attribute__((address_space(1))) unsigned int glb_u32;
__device__ __forceinline__ void gl_lds16(const void* g, void* l) {
  __builtin_amdgcn_global_load_lds((glb_u32*)g, (lds_u32*)l, 16, 0, 0);
}

__device__ __forceinline__ unsigned short f2b(float f) {
  union { float f; unsigned int u; } v; v.f = f;
  unsigned int r = (v.u + 0x7FFFu + ((v.u >> 16) & 1u)) >> 16;
  return (unsigned short)r;
}
__device__ __forceinline__ void up2(unsigned int u, float& a, float& b) {
  union { unsigned int x; float f; } lo, hi;
  lo.x = u << 16; hi.x = u & 0xffff0000u;
  a = lo.f; b = hi.f;
}
__device__ __forceinline__ void up16(uint4 u0, uint4 u1, float* f) {
  up2(u0.x, f[0], f[1]);  up2(u0.y, f[2], f[3]);
  up2(u0.z, f[4], f[5]);  up2(u0.w, f[6], f[7]);
  up2(u1.x, f[8], f[9]);  up2(u1.y, f[10], f[11]);
  up2(u1.z, f[12], f[13]); up2(u1.w, f[14], f[15]);
}

// ================= stage 1 bodies (independent work, fused dispatch) =================
__device__ __forceinline__
void wcast_body(const float* Wq, const float* Wkv, const float* Wp,
                const float* W1, const float* W2,
                unsigned short* oQKV, unsigned short* oP,
                unsigned short* o1, unsigned short* o2,
                const float* rp_w1, const float* rp_g, const float* rp_b,
                const float* rp_m, const float* rp_v, const float* rp_w2,
                float4* w1f, float4* W2t, int blk) {
  if (blk == 3072) {            // prep: fold rp BN into w1, reduce rp_w2 over heads
    int c = threadIdx.x;
    float s  = rp_g[c] / sqrtf(rp_v[c] + EPSBN);
    float b0 = rp_b[c] - rp_m[c] * s;
    w1f[c] = make_float4(rp_w1[c*3+0]*s, rp_w1[c*3+1]*s, rp_w1[c*3+2]*s, b0);
    float a0=0.f,a1=0.f,a2=0.f,a3=0.f;
    for (int o = 0; o < 64; o++) {
      a0 += rp_w2[(      o)*CC + c];
      a1 += rp_w2[( 64 + o)*CC + c];
      a2 += rp_w2[(128 + o)*CC + c];
      a3 += rp_w2[(192 + o)*CC + c];
    }
    W2t[c] = make_float4(a0,a1,a2,a3);
    return;
  }
  int i = blk * 256 + threadIdx.x;          // 786432 total
  if (i < 65536)        oQKV[i] = f2b(Wq[i]);
  else if (i < 196608)  oQKV[i] = f2b(Wkv[i - 65536]);
  else if (i < 262144)  oP[i - 196608] = f2b(Wp[i - 196608]);
  else if (i < 524288)  o1[i - 262144] = f2b(W1[i - 262144]);
  else                  o2[i - 524288] = f2b(W2[i - 524288]);
}

__device__ __forceinline__
void xcast_body(const float* x, unsigned short* xb, float* xf,
                int bx, int by, int bz) {
  __shared__ float T[64][65];
  int n0 = bx * 64, c0 = by * 64, bb = bz;
  int tid = threadIdx.x;
  {
    int crow = tid >> 2, ns = (tid & 3) * 16;
    const float* xp = x + ((size_t)(bb*CC + c0 + crow))*NPT + n0 + ns;
#pragma unroll
    for (int i = 0; i < 4; i++) {
      float4 v = ((const float4*)xp)[i];
      T[crow][ns + i*4 + 0] = v.x; T[crow][ns + i*4 + 1] = v.y;
      T[crow][ns + i*4 + 2] = v.z; T[crow][ns + i*4 + 3] = v.w;
    }
  }
  __syncthreads();
  {
    int nrow = tid >> 2, cs = (tid & 3) * 16;
    float vals[16];
#pragma unroll
    for (int i = 0; i < 16; i++) vals[i] = T[cs + i][nrow];
    size_t orow = ((size_t)(bb*NPT + n0 + nrow))*CC + c0 + cs;
#pragma unroll
    for (int i = 0; i < 4; i++)
      *(float4*)&xf[orow + i*4] = make_float4(vals[i*4], vals[i*4+1], vals[i*4+2], vals[i*4+3]);
    unsigned short us[16];
#pragma unroll
    for (int i = 0; i < 16; i++) us[i] = f2b(vals[i]);
    *(uint4*)&xb[orow]     = *(const uint4*)&us[0];
    *(uint4*)&xb[orow + 8] = *(const uint4*)&us[8];
  }
}

// KNN stage 1: packed-u32 min/max sorted-insert network, 2-op step.
// MSTEP order matters: max FIRST into a fresh SSA temp (key renames), then min
// IN-PLACE on the list register -> v_max_u32 + v_min_u32, no v_mov (the old
// t=min;key=max;K=t form forced a 3rd mov per step — R14 post-mortem, 72 instr/eval).
#define MSTEP(K) { unsigned int nk = max(key, K); K = min(key, K); key = nk; }
#define MPROC(M4, MI) { \
    float nd = fmaf(qx2, (M4).x, fmaf(qy2, (M4).y, fmaf(qz2, (M4).z, (M4).w + qsq))); \
    nd = fmaxf(nd, 0.f); \
    unsigned int key = (__float_as_uint(nd) & 0xFFFFFE00u) | (unsigned int)(MI); \
    MSTEP(k0)  MSTEP(k1)  MSTEP(k2)  MSTEP(k3) \
    MSTEP(k4)  MSTEP(k5)  MSTEP(k6)  MSTEP(k7) \
    MSTEP(k8)  MSTEP(k9)  MSTEP(k10) MSTEP(k11) \
    MSTEP(k12) MSTEP(k13) MSTEP(k14) MSTEP(k15) }
__device__ __forceinline__
void knn_partial_body(const float* xyz, float4* Pp, int s, int qg, int b) {
  __shared__ float4 sp[512];    // (x, y, z, |p|^2)
  const float* base = xyz + (size_t)b * 3 * NPT;
  int c0 = s * 512;
  for (int i = threadIdx.x; i < 512; i += 256) {
    float mx = base[c0 + i], my = base[NPT + c0 + i], mz = base[2*NPT + c0 + i];
    sp[i] = make_float4(mx, my, mz, mx*mx + my*my + mz*mz);
  }
  int lane = threadIdx.x & 63;
  int wv   = threadIdx.x >> 6;
  int qn   = qg * 64 + lane;
  float qx = base[qn], qy = base[NPT + qn], qz = base[2*NPT + qn];
  float qsq = qx*qx + qy*qy + qz*qz;
  float qx2 = -2.f*qx, qy2 = -2.f*qy, qz2 = -2.f*qz;
  __syncthreads();

  unsigned int k0=0xFFFFFFFFu,k1=0xFFFFFFFFu,k2=0xFFFFFFFFu,k3=0xFFFFFFFFu,
               k4=0xFFFFFFFFu,k5=0xFFFFFFFFu,k6=0xFFFFFFFFu,k7=0xFFFFFFFFu,
               k8=0xFFFFFFFFu,k9=0xFFFFFFFFu,k10=0xFFFFFFFFu,k11=0xFFFFFFFFu,
               k12=0xFFFFFFFFu,k13=0xFFFFFFFFu,k14=0xFFFFFFFFu,k15=0xFFFFFFFFu;

  int mbase = wv * 128;
  for (int mm = 0; mm < 128; mm += 4) {
    int m = mbase + mm;
    float4 a = sp[m], bq = sp[m+1], cq = sp[m+2], dq = sp[m+3];
    MPROC(a,  m)
    MPROC(bq, m+1)
    MPROC(cq, m+2)
    MPROC(dq, m+3)
  }

  int gq = b * NPT + qn;
  float4* out = Pp + (size_t)gq * 256 + (s*4 + wv)*8;
#define UNP(K) __uint_as_float(K & 0xFFFFFE00u), __int_as_float(c0 + (int)(K & 0x1FFu))
  out[0] = make_float4(UNP(k0),  UNP(k1));
  out[1] = make_float4(UNP(k2),  UNP(k3));
  out[2] = make_float4(UNP(k4),  UNP(k5));
  out[3] = make_float4(UNP(k6),  UNP(k7));
  out[4] = make_float4(UNP(k8),  UNP(k9));
  out[5] = make_float4(UNP(k10), UNP(k11));
  out[6] = make_float4(UNP(k12), UNP(k13));
  out[7] = make_float4(UNP(k14), UNP(k15));
#undef UNP
}

// stage1 fused dispatch: [0,512) xcast | [512,3585) wcast | [3585,4609) knn_partial.
__global__ __launch_bounds__(256) __attribute__((amdgpu_waves_per_eu(1, 4)))
void stage1_kernel(const float* x, unsigned short* xb, float* xf,
                   const float* xyz, float4* Pp,
                   const float* Wq, const float* Wkv, const float* Wp,
                   const float* W1, const float* W2,
                   unsigned short* oQKV, unsigned short* oP,
                   unsigned short* o1, unsigned short* o2,
                   const float* rp_w1, const float* rp_g, const float* rp_b,
                   const float* rp_m, const float* rp_v, const float* rp_w2,
                   float4* w1f, float4* W2t) {
  int bi = blockIdx.x;
  if (bi < 512) {
    xcast_body(x, xb, xf, bi & 63, (bi >> 6) & 3, bi >> 8);
  } else if (bi < 3585) {
    wcast_body(Wq, Wkv, Wp, W1, W2, oQKV, oP, o1, o2,
               rp_w1, rp_g, rp_b, rp_m, rp_v, rp_w2, w1f, W2t, bi - 512);
  } else {
    int i = bi - 3585;
    knn_partial_body(xyz, Pp, i & 7, (i >> 3) & 63, i >> 9);
  }
}

// ================= stage 2: knn_merge + qkv GEMM (independent, fused) ================
__device__ __forceinline__
void knn_merge_body(const float4* Pp, int* idx_out, int blk) {
  int wv   = threadIdx.x >> 6;
  int lane = threadIdx.x & 63;
  int gq   = blk * 4 + wv;
  float d[8]; int ii[8];
  const float4* base = Pp + (size_t)gq * 256;
#pragma unroll
  for (int j = 0; j < 4; j++) {
    float4 v = base[j*64 + lane];
    d[2*j+0] = v.x; ii[2*j+0] = __float_as_int(v.y);
    d[2*j+1] = v.z; ii[2*j+1] = __float_as_int(v.w);
  }
  for (int sel = 0; sel < 16; sel++) {
    float bd = 3.5e38f; int bi = 0x7fffffff;
#pragma unroll
    for (int t = 0; t < 8; t++) {
      bool better = (d[t] < bd) || (d[t] == bd && ii[t] < bi);
      if (better) { bd = d[t]; bi = ii[t]; }
    }
#pragma unroll
    for (int off = 1; off < 64; off <<= 1) {
      float od = __shfl_xor(bd, off, 64);
      int   oi = __shfl_xor(bi, off, 64);
      if (od < bd || (od == bd && oi < bi)) { bd = od; bi = oi; }
    }
#pragma unroll
    for (int t = 0; t < 8; t++)
      if (ii[t] == bi) d[t] = 3.5e38f;
    if (lane == 0) idx_out[gq*16 + sel] = bi;
  }
}

// ------- MFMA bf16 GEMM v3: NT-templated N-tile (NT*64 rows) ------------------------
struct MG {
  const unsigned short* A; const unsigned short* Wt; int K; int M;
  unsigned short* OutB; float* OutF;
  const float* bias; const float* resid;
  const float* bng; const float* bnb; const float* bnm; const float* bnv;
};

template<int EPI, int NT>
__device__ __forceinline__ void mgemm_body(const MG& p, int bx, int by, int bz) {
  __shared__ unsigned short As[NT*64*64];
  __shared__ unsigned short Bs[64*64];
  const int tid  = threadIdx.x;
  const int bb   = bz;
  const int n0   = bx * (NT*64);
  const int m0   = by * 64;
  const int lane = tid & 63;
  const int wv   = tid >> 6;
  const int l15  = lane & 15;
  const int quad = lane >> 4;
  const int K    = p.K;
  const int WR   = NT*16;                   // wave row span

  f32x4 acc[NT][4];
#pragma unroll
  for (int i = 0; i < NT; i++)
#pragma unroll
    for (int j = 0; j < 4; j++) acc[i][j] = (f32x4){0.f, 0.f, 0.f, 0.f};

  const int srow = wv*8 + (lane >> 3);
  const int pseg = lane & 7;
  const unsigned short* Abase = p.A  + (size_t)bb*NPT*K;

  for (int c0 = 0; c0 < K; c0 += 64) {
#pragma unroll
    for (int t = 0; t < NT*2; t++) {
      int row = t*32 + srow;
      int ls  = pseg ^ (row & 7);
      gl_lds16(Abase + (size_t)(n0 + row)*K + c0 + ls*8,
               &As[wv*512 + t*2048 + lane*8]);
    }
#pragma unroll
    for (int t = 0; t < 2; t++) {
      int row = t*32 + srow;
      int ls  = pseg ^ (row & 7);
      gl_lds16(p.Wt + (size_t)(m0 + row)*K + c0 + ls*8,
               &Bs[wv*512 + t*2048 + lane*8]);
    }
    __syncthreads();
    short8 bf[4][2];
#pragma unroll
    for (int mt = 0; mt < 4; mt++)
#pragma unroll
      for (int kk = 0; kk < 2; kk++) {
        int row = mt*16 + l15;
        int ps  = (kk*4 + quad) ^ (row & 7);
        bf[mt][kk] = *(const short8*)&Bs[row*64 + ps*8];
      }
#pragma unroll
    for (int nt = 0; nt < NT; nt++)
#pragma unroll
      for (int kk = 0; kk < 2; kk++) {
        int row = wv*WR + nt*16 + l15;
        int ps  = (kk*4 + quad) ^ (row & 7);
        short8 af = *(const short8*)&As[row*64 + ps*8];
#pragma unroll
        for (int mt = 0; mt < 4; mt++)
          acc[nt][mt] = __builtin_amdgcn_mfma_f32_16x16x32_bf16(af, bf[mt][kk], acc[nt][mt], 0, 0, 0);
      }
    __syncthreads();
  }

  if (EPI == 0 || EPI == 1) {
    float bs[4];
#pragma unroll
    for (int mt = 0; mt < 4; mt++)
      bs[mt] = (EPI == 1) ? p.bias[m0 + mt*16 + l15] : 0.f;
#pragma unroll
    for (int nt = 0; nt < NT; nt++)
#pragma unroll
      for (int reg = 0; reg < 4; reg++) {
        size_t row = ((size_t)(bb*NPT + n0 + wv*WR + nt*16 + quad*4 + reg))*p.M + m0;
#pragma unroll
        for (int mt = 0; mt < 4; mt++) {
          float v = acc[nt][mt][reg] + bs[mt];
          if (EPI == 1) v = fmaxf(v, 0.f);
          p.OutB[row + mt*16 + l15] = f2b(v);
        }
      }
  } else if (EPI == 2) {
    float sc[4], sh[4];
#pragma unroll
    for (int mt = 0; mt < 4; mt++) {
      int m = m0 + mt*16 + l15;
      float s = p.bng[m] / sqrtf(p.bnv[m] + EPSBN);
      sc[mt] = s; sh[mt] = p.bnb[m] - p.bnm[m]*s;
    }
#pragma unroll
    for (int nt = 0; nt < NT; nt++)
#pragma unroll
      for (int reg = 0; reg < 4; reg++) {
        size_t row = ((size_t)(bb*NPT + n0 + wv*WR + nt*16 + quad*4 + reg))*p.M + m0;
#pragma unroll
        for (int mt = 0; mt < 4; mt++) {
          float r = p.resid[row + mt*16 + l15];
          float v = (acc[nt][mt][reg] + r)*sc[mt] + sh[mt];
          p.OutF[row + mt*16 + l15] = v;
          p.OutB[row + mt*16 + l15] = f2b(v);
        }
      }
  } else {  // EPI == 3
    __shared__ float Tb[4][4][16*17];
    float sc[4], sh[4], bs[4];
#pragma unroll
    for (int mt = 0; mt < 4; mt++) {
      int m = m0 + mt*16 + l15;
      float s = p.bng[m] / sqrtf(p.bnv[m] + EPSBN);
      sc[mt] = s; sh[mt] = p.bnb[m] - p.bnm[m]*s;
      bs[mt] = p.bias[m];
    }
#pragma unroll
    for (int nt = 0; nt < NT; nt++) {
#pragma unroll
      for (int reg = 0; reg < 4; reg++) {
        size_t row = ((size_t)(bb*NPT + n0 + wv*WR + nt*16 + quad*4 + reg))*p.M + m0;
#pragma unroll
        for (int mt = 0; mt < 4; mt++) {
          float r = p.resid[row + mt*16 + l15];
          float v = (acc[nt][mt][reg] + bs[mt] + r)*sc[mt] + sh[mt];
          Tb[wv][mt][(quad*4 + reg)*17 + l15] = v;
        }
      }
      __syncthreads();
#pragma unroll
      for (int mt = 0; mt < 4; mt++)
#pragma unroll
        for (int reg = 0; reg < 4; reg++) {
          float v = Tb[wv][mt][l15*17 + quad*4 + reg];
          p.OutF[((size_t)(bb*p.M + m0 + mt*16 + quad*4 + reg))*NPT
                 + n0 + wv*WR + nt*16 + l15] = v;
        }
      __syncthreads();
    }
  }
}

template<int EPI, int NT>
__global__ __launch_bounds__(256)
void mgemm_kernel(MG p) { mgemm_body<EPI, NT>(p, blockIdx.x, blockIdx.y, blockIdx.z); }

// stage2 fused: [0,2048) knn_merge | [2048,2816) qkv GEMM (grid 32x12x2 linearized)
__global__ __launch_bounds__(256)
void stage2_kernel(const float4* Pp, int* idx, MG pqkv) {
  int bi = blockIdx.x;
  if (bi < 2048) {
    knn_merge_body(Pp, idx, bi);
  } else {
    int i = bi - 2048;
    mgemm_body<0, 2>(pqkv, i & 31, (i >> 5) % 12, i / 384);
  }
}

// ---------------- fused attention v4: 4 points/block, shared weight reads ----------
__global__ __launch_bounds__(256, 4)
void attn_kernel(const unsigned short* __restrict__ qkv, const float4* __restrict__ w1f,
                 const float4* __restrict__ W2t, const float* __restrict__ xyz,
                 const int* __restrict__ idx, unsigned short* __restrict__ attn_b) {
  __shared__ float4 sw1[256];
  __shared__ float4 sw2[256];
  __shared__ int   sidx[4][16];
  __shared__ float srel[4][16][4];
  __shared__ float sbias[4][16][4];
  __shared__ float red[4][16*68];
  int tid = threadIdx.x;
  int bn0 = blockIdx.x * 4;
  int b   = bn0 >> 12;
  sw1[tid] = w1f[tid];
  sw2[tid] = W2t[tid];
  if (tid < 64) {
    int p = tid >> 4, kk = tid & 15;
    int bn = bn0 + p, n = bn & 4095;
    int j = idx[bn*16 + kk];
    sidx[p][kk] = j;
    const float* pb = xyz + (size_t)b * 3 * NPT;
    srel[p][kk][0] = pb[j]         - pb[n];
    srel[p][kk][1] = pb[NPT + j]   - pb[NPT + n];
    srel[p][kk][2] = pb[2*NPT + j] - pb[2*NPT + n];
  }
  __syncthreads();
  {  // ---- bias phase: 4 points per weight read ----
    int kk = tid >> 4, cs = tid & 15;
    float rx[4], ry[4], rz[4], h[4][4];
#pragma unroll
    for (int p = 0; p < 4; p++) {
      rx[p] = srel[p][kk][0]; ry[p] = srel[p][kk][1]; rz[p] = srel[p][kk][2];
#pragma unroll
      for (int q = 0; q < 4; q++) h[p][q] = 0.f;
    }
#pragma unroll
    for (int i = 0; i < 16; i++) {
      int c = cs*16 + ((i + cs) & 15);
      float4 w  = sw1[c];
      float4 w2 = sw2[c];
#pragma unroll
      for (int p = 0; p < 4; p++) {
        float t0 = fmaxf(fmaf(rx[p], w.x, fmaf(ry[p], w.y, fmaf(rz[p], w.z, w.w))), 0.f);
        h[p][0] = fmaf(t0, w2.x, h[p][0]); h[p][1] = fmaf(t0, w2.y, h[p][1]);
        h[p][2] = fmaf(t0, w2.z, h[p][2]); h[p][3] = fmaf(t0, w2.w, h[p][3]);
      }
    }
#pragma unroll
    for (int off = 1; off < 16; off <<= 1)
#pragma unroll
      for (int p = 0; p < 4; p++)
#pragma unroll
        for (int q = 0; q < 4; q++)
          h[p][q] += __shfl_xor(h[p][q], off, 64);
    if (cs == 0)
#pragma unroll
      for (int p = 0; p < 4; p++)
#pragma unroll
        for (int q = 0; q < 4; q++) sbias[p][kk][q] = h[p][q];
  }
  __syncthreads();
  // ---- attention phase: 4 points serial ----
  int wv   = tid >> 6;
  int lane = tid & 63;
  int k    = lane >> 2;
  int c4   = lane & 3;
  int ch0  = wv*64 + c4*16;
  size_t base = (size_t)(b*NPT) * 768;
#pragma unroll 1
  for (int p = 0; p < 4; p++) {
    int bn = bn0 + p;
    size_t rowq = (size_t)bn * 768;
    float qf[16];
    {
      uint4 q0 = *(const uint4*)(qkv + rowq + ch0);
      uint4 q1 = *(const uint4*)(qkv + rowq + ch0 + 8);
      up16(q0, q1, qf);
    }
    int j = sidx[p][k];
    float dot = 0.f;
    {
      const unsigned short* krow = qkv + base + (size_t)j*768 + 256 + ch0;
      uint4 k0 = *(const uint4*)(krow);
      uint4 k1 = *(const uint4*)(krow + 8);
      float kf[16];
      up16(k0, k1, kf);
#pragma unroll
      for (int i = 0; i < 16; i++) dot = fmaf(qf[i], kf[i], dot);
    }
    dot += __shfl_xor(dot, 1, 64);
    dot += __shfl_xor(dot, 2, 64);
    float logit = dot * 0.125f + sbias[p][k][wv];
    float mx = logit;
#pragma unroll
    for (int off = 4; off < 64; off <<= 1) mx = fmaxf(mx, __shfl_xor(mx, off, 64));
    float e = __expf(logit - mx);
    float ssum = e;
#pragma unroll
    for (int off = 4; off < 64; off <<= 1) ssum += __shfl_xor(ssum, off, 64);
    float w = e / ssum;
    {
      const unsigned short* vrow = qkv + base + (size_t)j*768 + 512 + ch0;
      uint4 v0 = *(const uint4*)(vrow);
      uint4 v1 = *(const uint4*)(vrow + 8);
      float vf[16];
      up16(v0, v1, vf);
      float* dst = &red[wv][k*68 + c4*16];
#pragma unroll
      for (int g = 0; g < 4; g++)
        ((float4*)dst)[g] = make_float4(w*vf[g*4], w*vf[g*4+1], w*vf[g*4+2], w*vf[g*4+3]);
    }
    __syncthreads();
    float o = 0.f;
#pragma unroll
    for (int kk2 = 0; kk2 < 16; kk2++) o += red[wv][kk2*68 + lane];
    attn_b[(size_t)bn*256 + wv*64 + lane] = f2b(o);
    __syncthreads();
  }
}

extern "C" void kernel_launch(void* const* d_in, const int* in_sizes, int n_in,
                              void* d_out, int out_size, void* d_ws, size_t ws_size,
                              hipStream_t stream) {
  const float* x     = (const float*)d_in[0];
  const float* xyz   = (const float*)d_in[1];
  const float* Wq    = (const float*)d_in[2];
  const float* Wkv   = (const float*)d_in[3];
  const float* Wproj = (const float*)d_in[4];
  const float* rp_w1 = (const float*)d_in[5];
  const float* rp_g  = (const float*)d_in[6];
  const float* rp_b  = (const float*)d_in[7];
  const float* rp_m  = (const float*)d_in[8];
  const float* rp_v  = (const float*)d_in[9];
  const float* rp_w2 = (const float*)d_in[10];
  const float* bn1_g = (const float*)d_in[11];
  const float* bn1_b = (const float*)d_in[12];
  const float* bn1_m = (const float*)d_in[13];
  const float* bn1_v = (const float*)d_in[14];
  const float* bn2_g = (const float*)d_in[15];
  const float* bn2_b = (const float*)d_in[16];
  const float* bn2_m = (const float*)d_in[17];
  const float* bn2_v = (const float*)d_in[18];
  const float* ffn_w1 = (const float*)d_in[19];
  const float* ffn_b1 = (const float*)d_in[20];
  const float* ffn_w2 = (const float*)d_in[21];
  const float* ffn_b2 = (const float*)d_in[22];

  char* ws = (char*)d_ws;
  // static region
  float4* w1f = (float4*)(ws + 0);                         //   4 KB
  float4* W2t = (float4*)(ws + 4096);                      //   4 KB
  int*    idx = (int*)  (ws + 8192);                       // 512 KB
  // reuse region A (32 MB): KNN scratch first, then post-attn tensors
  const size_t oA = 532480;
  float4*         Pp     = (float4*)(ws + oA);             // 32 MB [B*N][512] (d,idx)
  unsigned short* attn_b = (unsigned short*)(ws + oA);                 //  4 MB bf16 [B][N][256]
  float*          x1f    = (float*)(ws + oA + (4u<<20));               //  8 MB fp32 [B][N][256]
  unsigned short* x1b    = (unsigned short*)(ws + oA + (12u<<20));     //  4 MB bf16 [B][N][256]
  unsigned short* h_b    = (unsigned short*)(ws + oA + (16u<<20));     // 16 MB bf16 [B][N][1024]
  // region B: weights + casted x + qkv
  const size_t oB = oA + (32u<<20);
  unsigned short* Wqkv_b  = (unsigned short*)(ws + oB);                // 384 KB [768][256]
  unsigned short* Wproj_b = (unsigned short*)(ws + oB + 393216);       // 128 KB
  unsigned short* W1_b    = (unsigned short*)(ws + oB + 524288);       // 512 KB
  unsigned short* W2_b    = (unsigned short*)(ws + oB + 1048576);      // 512 KB
  unsigned short* xb      = (unsigned short*)(ws + oB + 1572864);      //   4 MB bf16 [B][N][256]
  float*          xf      = (float*)(ws + oB + 1572864 + (4u<<20));    //   8 MB fp32 [B][N][256]
  unsigned short* qkv     = (unsigned short*)(ws + oB + 1572864 + (12u<<20)); // 12 MB bf16 [B][N][768]

  stage1_kernel<<<4609, 256, 0, stream>>>(x, xb, xf, xyz, Pp,
                                          Wq, Wkv, Wproj, ffn_w1, ffn_w2,
                                          Wqkv_b, Wproj_b, W1_b, W2_b,
                                          rp_w1, rp_g, rp_b, rp_m, rp_v, rp_w2,
                                          w1f, W2t);

  MG pqkv = {xb, Wqkv_b, 256, 768, qkv, nullptr,
             nullptr, nullptr, nullptr, nullptr, nullptr, nullptr};
  stage2_kernel<<<2816, 256, 0, stream>>>(Pp, idx, pqkv);

  attn_kernel<<<(BB*NPT)/4, 256, 0, stream>>>(qkv, w1f, W2t, xyz, idx, attn_b);

  MG pproj = {attn_b, Wproj_b, 256, 256, x1b, x1f,
              nullptr, xf, bn1_g, bn1_b, bn1_m, bn1_v};
  mgemm_kernel<2, 1><<<dim3(64, 4, BB), 256, 0, stream>>>(pproj);

  MG pf1 = {x1b, W1_b, 256, 1024, h_b, nullptr,
            ffn_b1, nullptr, nullptr, nullptr, nullptr, nullptr};
  mgemm_kernel<1, 2><<<dim3(32, 16, BB), 256, 0, stream>>>(pf1);

  MG pf2 = {h_b, W2_b, 1024, 256, nullptr, (float*)d_out,
            ffn_b2, x1f, bn2_g, bn2_b, bn2_m, bn2_v};
  mgemm_kernel<3, 1><<<dim3(64, 4, BB), 256, 0, stream>>>(pf2);
}